// Round 12
// baseline (351.354 us; speedup 1.0000x reference)
//
#include <hip/hip_runtime.h>
#include <math.h>

#define BB   16
#define CIN  16
#define LL   1024
#define DD   128
#define NHH  8
#define DHH  16
#define DF   512

#define INVS 0.9999950000374998f   // 1/sqrt(1+1e-5)
#define QSCALE2 0.12751743f        // (1/sqrt(128)) * log2(e)  -> softmax in exp2 domain

typedef __attribute__((ext_vector_type(2))) float f32x2;
typedef __attribute__((ext_vector_type(4))) float f32x4;
typedef __attribute__((ext_vector_type(8))) __bf16 bf16x8;

// tanh-form GELU: v*sigmoid(1.59577*(v+0.044715 v^3)), |err vs erf| <= ~4e-4
__device__ __forceinline__ float gelu_t(float v) {
    float u = v * v;
    float a = v * fmaf(-0.07135481627f, u, -1.5957691216f);
    float e = __expf(a);
    return v * __builtin_amdgcn_rcpf(1.0f + e);
}

// packed-f32 gelu (exp2-domain constants; same function, c-pair vectorized)
__device__ __forceinline__ f32x2 gelu2(f32x2 v) {
    f32x2 u = v * v;
    f32x2 a = v * (u * (-0.10294425f) + (-2.3022082f));   // -z/ln2
    f32x2 e;
    e.x = __builtin_amdgcn_exp2f(a.x);
    e.y = __builtin_amdgcn_exp2f(a.y);
    f32x2 r;
    r.x = __builtin_amdgcn_rcpf(1.0f + e.x);
    r.y = __builtin_amdgcn_rcpf(1.0f + e.y);
    return v * r;
}

__device__ __forceinline__ unsigned pkbf(float a, float b) {
    union { __bf16 h[2]; unsigned u; } z;
    z.h[0] = (__bf16)a; z.h[1] = (__bf16)b;
    return z.u;
}

#define SWZ(l) ((((l) & 7) ^ (((l) >> 2) & 6)))

// ---------- one prep kernel: all weight conversions + PE table ----------
__global__ __launch_bounds__(256) void k_prep(
    const float* __restrict__ c2w,
    const float* __restrict__ wq, const float* __restrict__ wk,
    const float* __restrict__ wv,
    const float* __restrict__ w1f, const float* __restrict__ w2f,
    const float* __restrict__ c1w, const float* __restrict__ c1b,
    const float* __restrict__ g1,  const float* __restrict__ bb1,
    __bf16* __restrict__ w2bf,  __bf16* __restrict__ wallbf,
    __bf16* __restrict__ w1fbf, __bf16* __restrict__ w2fbf,
    float* __restrict__ peb, float* __restrict__ w1A, float* __restrict__ b1A)
{
    const int bid = blockIdx.x;
    const int t = threadIdx.x;
    if (bid < 1024) {                       // w2: 1M elems
        int i = (bid * 256 + t) * 4;
        float4 v = *(const float4*)&c2w[i];
        union { __bf16 h[4]; float2 f2; } u;
        u.h[0] = (__bf16)v.x; u.h[1] = (__bf16)v.y;
        u.h[2] = (__bf16)v.z; u.h[3] = (__bf16)v.w;
        *(float2*)&w2bf[i] = u.f2;
    } else if (bid < 1072) {                // wq|wk|wv: 3*16384, wq pre-scaled (incl log2e)
        int e = ((bid - 1024) * 256 + t) * 4;
        int sel = e >> 14, r = e & 16383;
        const float* src = (sel == 0) ? wq : ((sel == 1) ? wk : wv);
        float sc = (sel == 0) ? QSCALE2 : 1.0f;
        float4 v = *(const float4*)&src[r];
        union { __bf16 h[4]; float2 f2; } u;
        u.h[0] = (__bf16)(v.x * sc); u.h[1] = (__bf16)(v.y * sc);
        u.h[2] = (__bf16)(v.z * sc); u.h[3] = (__bf16)(v.w * sc);
        *(float2*)&wallbf[e] = u.f2;
    } else if (bid < 1136) {                // w1f: 65536
        int e = ((bid - 1072) * 256 + t) * 4;
        float4 v = *(const float4*)&w1f[e];
        union { __bf16 h[4]; float2 f2; } u;
        u.h[0] = (__bf16)v.x; u.h[1] = (__bf16)v.y;
        u.h[2] = (__bf16)v.z; u.h[3] = (__bf16)v.w;
        *(float2*)&w1fbf[e] = u.f2;
    } else if (bid < 1200) {                // w2f: 65536
        int e = ((bid - 1136) * 256 + t) * 4;
        float4 v = *(const float4*)&w2f[e];
        union { __bf16 h[4]; float2 f2; } u;
        u.h[0] = (__bf16)v.x; u.h[1] = (__bf16)v.y;
        u.h[2] = (__bf16)v.z; u.h[3] = (__bf16)v.w;
        *(float2*)&w2fbf[e] = u.f2;
    } else if (bid < 1456) {                // PE table: 65536 (l, j) pairs
        int p = (bid - 1200) * 256 + t;
        int l = p >> 6, jj = p & 63;
        float ang = (float)l * expf(-0.14391156831212787f * (float)jj) * 0.125f;
        peb[l * 128 + jj * 2]     = sinf(ang);
        peb[l * 128 + jj * 2 + 1] = cosf(ang);
    } else {                                // fold BN1 into conv1 weights
        for (int o = t; o < DF; o += 256) {
            float A = g1[o] * INVS;
            #pragma unroll
            for (int tp = 0; tp < 7; tp++) w1A[o * 8 + tp] = c1w[o * 7 + tp] * A;
            w1A[o * 8 + 7] = 0.0f;
            b1A[o] = fmaf(c1b[o], A, bb1[o]);
        }
    }
}

// ---------- fused conv1+BN1+GELU -> bf16 MFMA conv2 GEMM -> BN2+GELU -> xsrc ----------
// 512 threads = 8 waves as 2(l-half) x 4(d-quarter); 32l x 128d tile, 32 chunks of 16 o
// A-read feeds 2 MFMAs (halved LDS reads); BLOAD inside MFMA phase (short breg lifetime)
__global__ __launch_bounds__(512, 4) void k_conv(
    const float* __restrict__ x,
    const float* __restrict__ w1A, const float* __restrict__ b1A,
    const __bf16* __restrict__ w2bf,
    const float* __restrict__ c2b, const float* __restrict__ g2,
    const float* __restrict__ bb2,
    float* __restrict__ xsrc)
{
    const int lt = blockIdx.x;      // 32 tiles of 32 l
    const int b  = blockIdx.y;      // 16
    const int t  = threadIdx.x;
    const int l0 = lt * 32;

    __shared__ float xs[CIN][40];
    __shared__ __align__(16) __bf16 Ab[2][32 * 256];

    for (int idx = t; idx < CIN * 38; idx += 512) {
        int c = idx / 38, i = idx % 38;
        int l = l0 - 3 + i;
        xs[c][i] = (l >= 0 && l < LL) ? x[(b * CIN + c) * LL + l] : 0.0f;
    }
    __syncthreads();

    const int lane = t & 63;
    const int wv   = t >> 6;                             // 0..7
    const int ogu  = __builtin_amdgcn_readfirstlane(wv); // wave-uniform id
    const int mwu  = ogu >> 2;                           // 0..1 (l-half)
    const int nwu  = ogu & 3;                            // 0..3 (d-quarter)
    const int cp   = lane & 7;
    const int lqi  = lane >> 3;                          // 0..7
    const int c0   = cp * 2;
    const int lq   = lqi * 4;

    f32x2 xw2[10];
    #pragma unroll
    for (int j = 0; j < 10; j++)
        xw2[j] = (f32x2){xs[c0][lq + j], xs[c0 + 1][lq + j]};

    const int l15 = lane & 15, kg = lane >> 4;

    f32x4 acc[2];           // nf = 0,1 (two 16-d fragments)
    acc[0] = (f32x4){0.f, 0.f, 0.f, 0.f};
    acc[1] = (f32x4){0.f, 0.f, 0.f, 0.f};

#define CONV_CHUNK(BUF, CH) do { \
    _Pragma("unroll") \
    for (int j = 0; j < 2; j++) { \
        int o = (CH) * 16 + ogu * 2 + j; \
        f32x4 wA = *(const f32x4*)&w1A[o * 8]; \
        f32x4 wB = *(const f32x4*)&w1A[o * 8 + 4]; \
        float bias = b1A[o]; \
        int kcol = (ogu * 2 + j) * 16 + c0; \
        _Pragma("unroll") \
        for (int dl = 0; dl < 4; dl++) { \
            f32x2 s = (f32x2){bias, bias}; \
            s = s + xw2[dl]     * wA[0]; \
            s = s + xw2[dl + 1] * wA[1]; \
            s = s + xw2[dl + 2] * wA[2]; \
            s = s + xw2[dl + 3] * wA[3]; \
            s = s + xw2[dl + 4] * wB[0]; \
            s = s + xw2[dl + 5] * wB[1]; \
            s = s + xw2[dl + 6] * wB[2]; \
            f32x2 g = gelu2(s); \
            int l = lq + dl; \
            *(unsigned*)&Ab[BUF][l * 256 + (kcol ^ (SWZ(l) << 3))] = pkbf(g.x, g.y); \
        } \
    } \
} while (0)

// BLOAD fused into the MFMA phase: breg lifetime is this phase only
#define MFMA_CHUNK(BUF, CH) do { \
    bf16x8 breg[16]; \
    _Pragma("unroll") \
    for (int nf = 0; nf < 2; nf++) \
        _Pragma("unroll") \
        for (int kk = 0; kk < 8; kk++) \
            breg[nf * 8 + kk] = *(const bf16x8*)&w2bf[ \
                (size_t)(nwu * 32 + nf * 16 + l15) * 8192 + (size_t)(CH) * 256 + kk * 32 + kg * 8]; \
    _Pragma("unroll") \
    for (int kk = 0; kk < 8; kk++) { \
        int kb = kk * 32 + kg * 8; \
        int r_ = mwu * 16 + l15; \
        bf16x8 af = *(const bf16x8*)&Ab[BUF][r_ * 256 + (kb ^ (SWZ(r_) << 3))]; \
        acc[0] = __builtin_amdgcn_mfma_f32_16x16x32_bf16(af, breg[kk],     acc[0], 0, 0, 0); \
        acc[1] = __builtin_amdgcn_mfma_f32_16x16x32_bf16(af, breg[8 + kk], acc[1], 0, 0, 0); \
    } \
} while (0)

    CONV_CHUNK(0, 0);
    __syncthreads();

    for (int ic = 0; ic < 30; ic += 2) {
        MFMA_CHUNK(0, ic);
        CONV_CHUNK(1, ic + 1);
        __syncthreads();

        MFMA_CHUNK(1, ic + 1);
        CONV_CHUNK(0, ic + 2);
        __syncthreads();
    }
    MFMA_CHUNK(0, 30);
    CONV_CHUNK(1, 31);
    __syncthreads();
    MFMA_CHUNK(1, 31);

    // epilogue: BN2 + GELU  (C: col=lane&15 -> d, row=(lane>>4)*4+r -> l)
    #pragma unroll
    for (int nf = 0; nf < 2; nf++) {
        int d = nwu * 32 + nf * 16 + l15;
        float A2 = g2[d] * INVS;
        float B2 = fmaf(c2b[d], A2, bb2[d]);
        #pragma unroll
        for (int r = 0; r < 4; r++) {
            int l = l0 + mwu * 16 + kg * 4 + r;
            xsrc[((size_t)b * LL + l) * DD + d] = gelu_t(fmaf(acc[nf][r], A2, B2));
        }
    }
#undef CONV_CHUNK
#undef MFMA_CHUNK
}

// ---------- qkv via MFMA: x_pos = xsrc + PE (bf16), out = x_pos @ W^T ----------
// 384 threads (6 waves): wave w covers 64 outputs of [q|k|v] (wq pre-scaled)
__global__ __launch_bounds__(384) void k_qkv(
    const float* __restrict__ xsrc, const float* __restrict__ peb,
    const __bf16* __restrict__ wallbf,
    __bf16* __restrict__ qo, __bf16* __restrict__ ko, __bf16* __restrict__ vo)
{
    const int lt = blockIdx.x, b = blockIdx.y;
    const int t = threadIdx.x;
    const int l0 = lt * 64;

    __shared__ __align__(16) __bf16 Xp[64 * 128];

    for (int e = t; e < 2048; e += 384) {
        int l = e >> 5, d0 = (e & 31) * 4;
        float4 xv = *(const float4*)&xsrc[((size_t)b * LL + l0 + l) * DD + d0];
        float4 pv = *(const float4*)&peb[(size_t)(l0 + l) * DD + d0];
        union { __bf16 h[4]; float2 f2; } u;
        u.h[0] = (__bf16)(xv.x + pv.x); u.h[1] = (__bf16)(xv.y + pv.y);
        u.h[2] = (__bf16)(xv.z + pv.z); u.h[3] = (__bf16)(xv.w + pv.w);
        *(float2*)&Xp[l * 128 + (d0 ^ (SWZ(l) << 3))] = u.f2;
    }
    __syncthreads();

    const int w = t >> 6, lane = t & 63;
    const int l15 = lane & 15, kg = lane >> 4;
    const int wsel = w >> 1, hb = w & 1;

    bf16x8 breg[16];
    #pragma unroll
    for (int nf = 0; nf < 4; nf++)
        #pragma unroll
        for (int kk = 0; kk < 4; kk++)
            breg[nf * 4 + kk] = *(const bf16x8*)&wallbf[
                (size_t)wsel * 16384 + (size_t)(hb * 64 + nf * 16 + l15) * 128 + kk * 32 + kg * 8];

    f32x4 acc[4][4];
    #pragma unroll
    for (int mf = 0; mf < 4; mf++)
        #pragma unroll
        for (int nf = 0; nf < 4; nf++) acc[mf][nf] = (f32x4){0.f, 0.f, 0.f, 0.f};

    #pragma unroll
    for (int kk = 0; kk < 4; kk++) {
        int kb = kk * 32 + kg * 8;
        bf16x8 af[4];
        #pragma unroll
        for (int mf = 0; mf < 4; mf++) {
            int r = mf * 16 + l15;
            af[mf] = *(const bf16x8*)&Xp[r * 128 + (kb ^ (SWZ(r) << 3))];
        }
        #pragma unroll
        for (int mf = 0; mf < 4; mf++)
            #pragma unroll
            for (int nf = 0; nf < 4; nf++)
                acc[mf][nf] = __builtin_amdgcn_mfma_f32_16x16x32_bf16(
                    af[mf], breg[nf * 4 + kk], acc[mf][nf], 0, 0, 0);
    }

    __bf16* op = (wsel == 0) ? qo : ((wsel == 1) ? ko : vo);
    #pragma unroll
    for (int mf = 0; mf < 4; mf++) {
        #pragma unroll
        for (int nf = 0; nf < 4; nf++) {
            int h = hb * 4 + nf;
            #pragma unroll
            for (int r = 0; r < 4; r++) {
                int l = l0 + mf * 16 + kg * 4 + r;
                op[(((size_t)b * NHH + h) * LL + l) * DHH + l15] = (__bf16)acc[mf][nf][r];
            }
        }
    }
}

// ---------- attention via MFMA: softmax(QK^T*s)@V + relbias@V  (flash, exp2 domain) ----------
__global__ __launch_bounds__(256) void k_attn(
    const __bf16* __restrict__ q, const __bf16* __restrict__ k,
    const __bf16* __restrict__ v, const float* __restrict__ rel,
    float* __restrict__ out)
{
    const int bh = blockIdx.x;           // 128
    const int qt = blockIdx.y;           // 8 tiles of 128 q
    const int h  = bh & 7;
    const int t  = threadIdx.x;
    const int w  = t >> 6, lane = t & 63;
    const int g  = lane >> 4, qi = lane & 15;
    const int xq = (qi & 7) << 3;
    const int qbase = qt * 128 + w * 32;

    __shared__ __align__(16) __bf16 lds[16384];
    __bf16* Vl = lds;                    // 4096
    __bf16* Pw = lds + 4096 + w * 2048;  // per-wave 2048
    __bf16* R0 = lds + 12288;            // 2048
    __bf16* R1 = lds + 14336;            // 2048

    for (int i = t; i < 2048; i += 256) {
        R0[i] = (__bf16)((i <= 2046) ? rel[(size_t)(2046 - i) * NHH + h] : 0.0f);
        R1[i] = (__bf16)((i <= 2045) ? rel[(size_t)(2045 - i) * NHH + h] : 0.0f);
    }

    bf16x8 qf[2];
    {
        union { unsigned u[4]; bf16x8 v8; } uz;
        uz.u[0] = uz.u[1] = uz.u[2] = uz.u[3] = 0u;
        #pragma unroll
        for (int n = 0; n < 2; n++) {
            qf[n] = uz.v8;
            if (g < 2)
                qf[n] = *(const bf16x8*)&q[((size_t)bh * LL + qbase + n * 16 + qi) * DHH + g * 8];
        }
    }

    f32x4 accp[2], accb[2];
    #pragma unroll
    for (int n = 0; n < 2; n++) {
        accp[n] = (f32x4){0.f, 0.f, 0.f, 0.f};
        accb[n] = (f32x4){0.f, 0.f, 0.f, 0.f};
    }
    float mrun[2] = {-INFINITY, -INFINITY};
    float lrun[2] = {0.f, 0.f};

    const f32x4 zero4 = (f32x4){0.f, 0.f, 0.f, 0.f};

// S is in log2 domain (q pre-scaled by 1/sqrt(128)*log2e) -> bare v_exp_f32
#define PROC_N(Sn, n) do { \
    float mx = Sn[0][0]; \
    _Pragma("unroll") \
    for (int f = 0; f < 8; f++) { \
        _Pragma("unroll") \
        for (int r = 0; r < 4; r++) if (f || r) mx = fmaxf(mx, Sn[f][r]); } \
    mx = fmaxf(mx, __shfl_xor(mx, 16, 64)); \
    mx = fmaxf(mx, __shfl_xor(mx, 32, 64)); \
    float mnew = fmaxf(mrun[n], mx); \
    float sf = __builtin_amdgcn_exp2f(mrun[n] - mnew); \
    mrun[n] = mnew; \
    lrun[n] *= sf; \
    accp[n][0] *= sf; accp[n][1] *= sf; accp[n][2] *= sf; accp[n][3] *= sf; \
    float ls = 0.f; \
    _Pragma("unroll") \
    for (int f = 0; f < 8; f++) { \
        float p0 = __builtin_amdgcn_exp2f(Sn[f][0] - mnew); \
        float p1 = __builtin_amdgcn_exp2f(Sn[f][1] - mnew); \
        float p2 = __builtin_amdgcn_exp2f(Sn[f][2] - mnew); \
        float p3 = __builtin_amdgcn_exp2f(Sn[f][3] - mnew); \
        ls += (p0 + p1) + (p2 + p3); \
        unsigned* pp = (unsigned*)(Pw + (qi * 128 + ((f * 16 + g * 4) ^ xq))); \
        pp[0] = pkbf(p0, p1); pp[1] = pkbf(p2, p3); \
    } \
    ls += __shfl_xor(ls, 16, 64); ls += __shfl_xor(ls, 32, 64); \
    lrun[n] += ls; \
    int qoff = 1023 - (qbase + (n) * 16 + qi) + k0; \
    _Pragma("unroll") \
    for (int c = 0; c < 4; c++) { \
        bf16x8 vf = *(const bf16x8*)&Vbuf[qi * 128 + ((c * 32 + g * 8) ^ xq)]; \
        bf16x8 pf = *(const bf16x8*)&Pw[qi * 128 + ((c * 32 + g * 8) ^ xq)]; \
        int idx = qoff + c * 32 + 8 * g; \
        const unsigned* tb = (const unsigned*)((idx & 1) ? R1 : R0); \
        unsigned s_ = (unsigned)idx >> 1; \
        union { unsigned u[4]; bf16x8 v8; } bu; \
        bu.u[0] = tb[s_]; bu.u[1] = tb[s_ + 1]; \
        bu.u[2] = tb[s_ + 2]; bu.u[3] = tb[s_ + 3]; \
        accp[n] = __builtin_amdgcn_mfma_f32_16x16x32_bf16(vf, pf, accp[n], 0, 0, 0); \
        accb[n] = __builtin_amdgcn_mfma_f32_16x16x32_bf16(vf, bu.v8, accb[n], 0, 0, 0); \
    } \
} while (0)

    for (int kt = 0; kt < 8; kt++) {
        const int k0 = kt * 128;
        {
            int kr = t >> 1, d0 = (t & 1) * 8;
            bf16x8 b8 = *(const bf16x8*)&v[((size_t)bh * LL + k0 + kr) * DHH + d0];
            __bf16* dst = Vl + (kt & 1) * 2048;
            #pragma unroll
            for (int i = 0; i < 8; i++) {
                int d = d0 + i;
                dst[d * 128 + (kr ^ ((d & 7) << 3))] = b8[i];
            }
        }
        __syncthreads();
        const __bf16* Vbuf = Vl + (kt & 1) * 2048;

        f32x4 S0[8], S1[8];
        #pragma unroll
        for (int f = 0; f < 8; f++) {
            bf16x8 kf = *(const bf16x8*)&k[((size_t)bh * LL + k0 + f * 16 + qi) * DHH + (g & 1) * 8];
            S0[f] = __builtin_amdgcn_mfma_f32_16x16x32_bf16(kf, qf[0], zero4, 0, 0, 0);
            S1[f] = __builtin_amdgcn_mfma_f32_16x16x32_bf16(kf, qf[1], zero4, 0, 0, 0);
        }

        PROC_N(S0, 0);
        PROC_N(S1, 1);
    }
#undef PROC_N

    #pragma unroll
    for (int n = 0; n < 2; n++) {
        float inv = 1.0f / lrun[n];
        float4 o;
        o.x = accp[n][0] * inv + accb[n][0];
        o.y = accp[n][1] * inv + accb[n][1];
        o.z = accp[n][2] * inv + accb[n][2];
        o.w = accp[n][3] * inv + accb[n][3];
        *(float4*)&out[((size_t)bh * LL + qbase + n * 16 + qi) * DHH + g * 4] = o;
    }
}

// ---------- LN(attn_out) ; att = LN(x_src + .) ----------
__global__ __launch_bounds__(256) void k_ln(
    const float* __restrict__ ao,  const float* __restrict__ xsrc,
    const float* __restrict__ lag, const float* __restrict__ lab,
    const float* __restrict__ l1g, const float* __restrict__ l1b,
    float* __restrict__ att)
{
    const int lt = blockIdx.x, b = blockIdx.y;
    const int t = threadIdx.x;
    const int l0 = lt * 64;
    __shared__ float tile[64][132];

    #pragma unroll
    for (int u = 0; u < 4; u++) {
        int cid = u * 256 + t;
        int hh = cid >> 7, rem = cid & 127;
        int l = rem >> 1, dh0 = (rem & 1) * 8;
        const float* src = &ao[(((size_t)b * NHH + hh) * LL + l0 + l) * DHH + dh0];
        float4 a0 = *(const float4*)src;
        float4 a1 = *(const float4*)(src + 4);
        *(float4*)&tile[l][hh * 16 + dh0]     = a0;
        *(float4*)&tile[l][hh * 16 + dh0 + 4] = a1;
    }
    __syncthreads();

    const int wid = t >> 6, lane = t & 63;
    float2 ga  = *(const float2*)&lag[lane * 2];
    float2 ba  = *(const float2*)&lab[lane * 2];
    float2 g1v = *(const float2*)&l1g[lane * 2];
    float2 b1v = *(const float2*)&l1b[lane * 2];

    for (int rr = 0; rr < 16; rr++) {
        int r = wid * 16 + rr;
        float2 vv = *(const float2*)&tile[r][lane * 2];
        float s = vv.x + vv.y, s2 = vv.x * vv.x + vv.y * vv.y;
        #pragma unroll
        for (int m = 1; m < 64; m <<= 1) { s += __shfl_xor(s, m, 64); s2 += __shfl_xor(s2, m, 64); }
        float mu = s * (1.f / 128.f);
        float var = s2 * (1.f / 128.f) - mu * mu;
        float rs = rsqrtf(var + 1e-5f);
        float o0 = (vv.x - mu) * rs * ga.x + ba.x;
        float o1 = (vv.y - mu) * rs * ga.y + ba.y;
        float2 xv = *(const float2*)&xsrc[((size_t)b * LL + l0 + r) * DD + lane * 2];
        float t0 = xv.x + o0, t1 = xv.y + o1;
        s = t0 + t1; s2 = t0 * t0 + t1 * t1;
        #pragma unroll
        for (int m = 1; m < 64; m <<= 1) { s += __shfl_xor(s, m, 64); s2 += __shfl_xor(s2, m, 64); }
        mu = s * (1.f / 128.f);
        var = s2 * (1.f / 128.f) - mu * mu;
        rs = rsqrtf(var + 1e-5f);
        float a0 = (t0 - mu) * rs * g1v.x + b1v.x;
        float a1 = (t1 - mu) * rs * g1v.y + b1v.y;
        float2 o = {a0, a1};
        *(float2*)&att[((size_t)b * LL + l0 + r) * DD + lane * 2] = o;
    }
}

// ---------- ff1 = relu(att @ w1^T + b1) -> bf16, MFMA ----------
__global__ __launch_bounds__(512) void k_ff1(
    const float* __restrict__ att, const __bf16* __restrict__ w1fbf,
    const float* __restrict__ b1f, __bf16* __restrict__ ff1b)
{
    const int lt = blockIdx.x, b = blockIdx.y;
    const int t = threadIdx.x;
    const int l0 = lt * 64;

    __shared__ __align__(16) __bf16 Ax[64 * 128];

    #pragma unroll
    for (int it = 0; it < 4; it++) {
        int e = it * 512 + t;
        int l = e >> 5, d0 = (e & 31) * 4;
        float4 xv = *(const float4*)&att[((size_t)b * LL + l0 + l) * DD + d0];
        union { __bf16 h[4]; float2 f2; } u;
        u.h[0] = (__bf16)xv.x; u.h[1] = (__bf16)xv.y;
        u.h[2] = (__bf16)xv.z; u.h[3] = (__bf16)xv.w;
        *(float2*)&Ax[l * 128 + (d0 ^ (SWZ(l) << 3))] = u.f2;
    }
    __syncthreads();

    const int w = t >> 6, lane = t & 63;
    const int l15 = lane & 15, kg = lane >> 4;

    bf16x8 breg[16];
    #pragma unroll
    for (int nf = 0; nf < 4; nf++)
        #pragma unroll
        for (int kk = 0; kk < 4; kk++)
            breg[nf * 4 + kk] = *(const bf16x8*)&w1fbf[
                (size_t)(w * 64 + nf * 16 + l15) * 128 + kk * 32 + kg * 8];

    f32x4 acc[4][4];
    #pragma unroll
    for (int mf = 0; mf < 4; mf++)
        #pragma unroll
        for (int nf = 0; nf < 4; nf++) acc[mf][nf] = (f32x4){0.f, 0.f, 0.f, 0.f};

    #pragma unroll
    for (int kk = 0; kk < 4; kk++) {
        int kb = kk * 32 + kg * 8;
        bf16x8 af[4];
        #pragma unroll
        for (int mf = 0; mf < 4; mf++) {
            int r = mf * 16 + l15;
            af[mf] = *(const bf16x8*)&Ax[r * 128 + (kb ^ (SWZ(r) << 3))];
        }
        #pragma unroll
        for (int mf = 0; mf < 4; mf++)
            #pragma unroll
            for (int nf = 0; nf < 4; nf++)
                acc[mf][nf] = __builtin_amdgcn_mfma_f32_16x16x32_bf16(
                    af[mf], breg[nf * 4 + kk], acc[mf][nf], 0, 0, 0);
    }

    #pragma unroll
    for (int nf = 0; nf < 4; nf++) {
        int n = w * 64 + nf * 16 + l15;
        float bias = b1f[n];
        #pragma unroll
        for (int mf = 0; mf < 4; mf++) {
            #pragma unroll
            for (int r = 0; r < 4; r++) {
                int l = l0 + mf * 16 + kg * 4 + r;
                float vv = fmaxf(acc[mf][nf][r] + bias, 0.0f);
                ff1b[((size_t)b * LL + l) * DF + n] = (__bf16)vv;
            }
        }
    }
}

// ---------- ff2 (MFMA, K=512) + bias + residual + LN2 + transpose-store ----------
__global__ __launch_bounds__(512) void k_ff2(
    const __bf16* __restrict__ ff1b, const __bf16* __restrict__ w2fbf,
    const float* __restrict__ b2f, const float* __restrict__ att,
    const float* __restrict__ l2g, const float* __restrict__ l2b,
    float* __restrict__ y)
{
    const int lt = blockIdx.x, b = blockIdx.y;
    const int t = threadIdx.x;
    const int l0 = lt * 64;

    __shared__ __align__(16) __bf16 Ax[64 * 512];   // 64KB; reused as yl after GEMM
    float* yl = (float*)Ax;                          // [64][132] overlay

    #pragma unroll
    for (int it = 0; it < 8; it++) {
        int g8 = it * 512 + t;                       // 4096 granules of 8
        int l = g8 >> 6, c8 = g8 & 63;
        bf16x8 v8 = *(const bf16x8*)&ff1b[((size_t)b * LL + l0 + l) * DF + c8 * 8];
        *(bf16x8*)&Ax[l * 512 + ((c8 * 8) ^ (SWZ(l) << 3))] = v8;
    }
    __syncthreads();

    const int w = t >> 6, lane = t & 63;
    const int l15 = lane & 15, kg = lane >> 4;
    const int d = w * 16 + l15;

    bf16x8 breg[16];
    #pragma unroll
    for (int kk = 0; kk < 16; kk++)
        breg[kk] = *(const bf16x8*)&w2fbf[(size_t)d * DF + kk * 32 + kg * 8];

    f32x4 acc[4];
    #pragma unroll
    for (int mf = 0; mf < 4; mf++) acc[mf] = (f32x4){0.f, 0.f, 0.f, 0.f};

    #pragma unroll
    for (int kk = 0; kk < 16; kk++) {
        int kb = kk * 32 + kg * 8;
        #pragma unroll
        for (int mf = 0; mf < 4; mf++) {
            int r = mf * 16 + l15;
            bf16x8 af = *(const bf16x8*)&Ax[r * 512 + (kb ^ (SWZ(r) << 3))];
            acc[mf] = __builtin_amdgcn_mfma_f32_16x16x32_bf16(af, breg[kk], acc[mf], 0, 0, 0);
        }
    }
    __syncthreads();   // Ax reads done; overlay as yl

    {
        float bias = b2f[d];
        #pragma unroll
        for (int mf = 0; mf < 4; mf++) {
            #pragma unroll
            for (int r = 0; r < 4; r++) {
                int l = mf * 16 + kg * 4 + r;
                float res = att[((size_t)b * LL + l0 + l) * DD + d];
                yl[l * 132 + d] = acc[mf][r] + bias + res;
            }
        }
    }
    __syncthreads();

    const int wid = t >> 6;
    float2 gv = *(const float2*)&l2g[lane * 2];
    float2 bv = *(const float2*)&l2b[lane * 2];
    for (int rr = 0; rr < 8; rr++) {
        int r = wid * 8 + rr;
        float2 vv = *(const float2*)&yl[r * 132 + lane * 2];
        float s = vv.x + vv.y, s2 = vv.x * vv.x + vv.y * vv.y;
        #pragma unroll
        for (int m = 1; m < 64; m <<= 1) { s += __shfl_xor(s, m, 64); s2 += __shfl_xor(s2, m, 64); }
        float mu = s * (1.f / 128.f);
        float var = s2 * (1.f / 128.f) - mu * mu;
        float rs = rsqrtf(var + 1e-5f);
        float o0 = (vv.x - mu) * rs * gv.x + bv.x;
        float o1 = (vv.y - mu) * rs * gv.y + bv.y;
        yl[r * 132 + lane * 2]     = o0;
        yl[r * 132 + lane * 2 + 1] = o1;
    }
    __syncthreads();

    {
        int dd = t >> 2, lh = (t & 3) * 16;
        #pragma unroll
        for (int i0 = 0; i0 < 16; i0 += 4) {
            float4 o = { yl[(lh + i0 + 0) * 132 + dd], yl[(lh + i0 + 1) * 132 + dd],
                         yl[(lh + i0 + 2) * 132 + dd], yl[(lh + i0 + 3) * 132 + dd] };
            *(float4*)&y[(size_t)b * DD * LL + (size_t)dd * LL + l0 + lh + i0] = o;
        }
    }
}

extern "C" void kernel_launch(void* const* d_in, const int* in_sizes, int n_in,
                              void* d_out, int out_size, void* d_ws, size_t ws_size,
                              hipStream_t stream)
{
    const float* x   = (const float*)d_in[0];
    const float* c1w = (const float*)d_in[1];
    const float* c1b = (const float*)d_in[2];
    const float* g1  = (const float*)d_in[3];
    const float* bb1 = (const float*)d_in[4];
    const float* c2w = (const float*)d_in[5];
    const float* c2b = (const float*)d_in[6];
    const float* g2  = (const float*)d_in[7];
    const float* bb2 = (const float*)d_in[8];
    const float* wq  = (const float*)d_in[9];
    const float* wk  = (const float*)d_in[10];
    const float* wv  = (const float*)d_in[11];
    const float* rel = (const float*)d_in[12];
    const float* lag = (const float*)d_in[13];
    const float* lab = (const float*)d_in[14];
    const float* l1g = (const float*)d_in[15];
    const float* l1b = (const float*)d_in[16];
    const float* l2g = (const float*)d_in[17];
    const float* l2b = (const float*)d_in[18];
    const float* w1f = (const float*)d_in[19];
    const float* b1f = (const float*)d_in[20];
    const float* w2f = (const float*)d_in[21];
    const float* b2f = (const float*)d_in[22];

    char* W = (char*)d_ws;
    const size_t MB = 1ull << 20;
    float*  xsrc   = (float*)(W);
    float*  abuf   = (float*)(W + 8 * MB);
    float*  attb   = (float*)(W + 16 * MB);
    __bf16* qbuf   = (__bf16*)(W + 24 * MB);
    __bf16* kbuf   = (__bf16*)(W + 28 * MB);
    __bf16* vbuf   = (__bf16*)(W + 32 * MB);
    __bf16* ff1b   = (__bf16*)(W + 36 * MB);
    __bf16* w2bf   = (__bf16*)(W + 52 * MB);
    __bf16* wallbf = (__bf16*)(W + 54 * MB);
    __bf16* w1fbf  = (__bf16*)(W + 54 * MB + 128 * 1024);
    __bf16* w2fbf  = (__bf16*)(W + 54 * MB + 256 * 1024);
    float*  peb    = (float*)(W + 54 * MB + 384 * 1024);
    float*  w1A    = (float*)(W + 54 * MB + 896 * 1024);
    float*  b1A    = (float*)(W + 54 * MB + 912 * 1024);

    k_prep<<<dim3(1457), dim3(256), 0, stream>>>(
        c2w, wq, wk, wv, w1f, w2f, c1w, c1b, g1, bb1,
        w2bf, wallbf, w1fbf, w2fbf, peb, w1A, b1A);
    k_conv<<<dim3(32, 16), dim3(512), 0, stream>>>(x, w1A, b1A, w2bf, c2b, g2, bb2, xsrc);
    k_qkv<<<dim3(16, 16), dim3(384), 0, stream>>>(xsrc, peb, wallbf, qbuf, kbuf, vbuf);
    k_attn<<<dim3(128, 8), dim3(256), 0, stream>>>(qbuf, kbuf, vbuf, rel, abuf);
    k_ln<<<dim3(16, 16), dim3(256), 0, stream>>>(abuf, xsrc, lag, lab, l1g, l1b, attb);
    k_ff1<<<dim3(16, 16), dim3(512), 0, stream>>>(attb, w1fbf, b1f, ff1b);
    k_ff2<<<dim3(16, 16), dim3(512), 0, stream>>>(ff1b, w2fbf, b2f, attb, l2g, l2b, (float*)d_out);
}

// Round 13
// 232.254 us; speedup vs baseline: 1.5128x; 1.5128x over previous
//
#include <hip/hip_runtime.h>
#include <math.h>

#define BB   16
#define CIN  16
#define LL   1024
#define DD   128
#define NHH  8
#define DHH  16
#define DF   512

#define INVS 0.9999950000374998f   // 1/sqrt(1+1e-5)
#define QSCALE2 0.12751743f        // (1/sqrt(128)) * log2(e)  -> softmax in exp2 domain

typedef __attribute__((ext_vector_type(2))) float f32x2;
typedef __attribute__((ext_vector_type(4))) float f32x4;
typedef __attribute__((ext_vector_type(8))) __bf16 bf16x8;

// tanh-form GELU: v*sigmoid(1.59577*(v+0.044715 v^3)), |err vs erf| <= ~4e-4
__device__ __forceinline__ float gelu_t(float v) {
    float u = v * v;
    float a = v * fmaf(-0.07135481627f, u, -1.5957691216f);
    float e = __expf(a);
    return v * __builtin_amdgcn_rcpf(1.0f + e);
}

// packed-f32 gelu (exp2-domain constants; same function, c-pair vectorized)
__device__ __forceinline__ f32x2 gelu2(f32x2 v) {
    f32x2 u = v * v;
    f32x2 a = v * (u * (-0.10294425f) + (-2.3022082f));   // -z/ln2
    f32x2 e;
    e.x = __builtin_amdgcn_exp2f(a.x);
    e.y = __builtin_amdgcn_exp2f(a.y);
    f32x2 r;
    r.x = __builtin_amdgcn_rcpf(1.0f + e.x);
    r.y = __builtin_amdgcn_rcpf(1.0f + e.y);
    return v * r;
}

__device__ __forceinline__ unsigned pkbf(float a, float b) {
    union { __bf16 h[2]; unsigned u; } z;
    z.h[0] = (__bf16)a; z.h[1] = (__bf16)b;
    return z.u;
}

#define SWZ(l) ((((l) & 7) ^ (((l) >> 2) & 6)))

// ---------- one prep kernel: weight conversions + PE table + attn rel tables ----------
__global__ __launch_bounds__(256) void k_prep(
    const float* __restrict__ c2w,
    const float* __restrict__ wq, const float* __restrict__ wk,
    const float* __restrict__ wv,
    const float* __restrict__ w1f, const float* __restrict__ w2f,
    const float* __restrict__ c1w, const float* __restrict__ c1b,
    const float* __restrict__ g1,  const float* __restrict__ bb1,
    const float* __restrict__ rel,
    __bf16* __restrict__ w2bf,  __bf16* __restrict__ wallbf,
    __bf16* __restrict__ w1fbf, __bf16* __restrict__ w2fbf,
    float* __restrict__ peb, float* __restrict__ w1A, float* __restrict__ b1A,
    __bf16* __restrict__ rtab)
{
    const int bid = blockIdx.x;
    const int t = threadIdx.x;
    if (bid < 1024) {                       // w2: 1M elems
        int i = (bid * 256 + t) * 4;
        float4 v = *(const float4*)&c2w[i];
        union { __bf16 h[4]; float2 f2; } u;
        u.h[0] = (__bf16)v.x; u.h[1] = (__bf16)v.y;
        u.h[2] = (__bf16)v.z; u.h[3] = (__bf16)v.w;
        *(float2*)&w2bf[i] = u.f2;
    } else if (bid < 1072) {                // wq|wk|wv: 3*16384, wq pre-scaled (incl log2e)
        int e = ((bid - 1024) * 256 + t) * 4;
        int sel = e >> 14, r = e & 16383;
        const float* src = (sel == 0) ? wq : ((sel == 1) ? wk : wv);
        float sc = (sel == 0) ? QSCALE2 : 1.0f;
        float4 v = *(const float4*)&src[r];
        union { __bf16 h[4]; float2 f2; } u;
        u.h[0] = (__bf16)(v.x * sc); u.h[1] = (__bf16)(v.y * sc);
        u.h[2] = (__bf16)(v.z * sc); u.h[3] = (__bf16)(v.w * sc);
        *(float2*)&wallbf[e] = u.f2;
    } else if (bid < 1136) {                // w1f: 65536
        int e = ((bid - 1072) * 256 + t) * 4;
        float4 v = *(const float4*)&w1f[e];
        union { __bf16 h[4]; float2 f2; } u;
        u.h[0] = (__bf16)v.x; u.h[1] = (__bf16)v.y;
        u.h[2] = (__bf16)v.z; u.h[3] = (__bf16)v.w;
        *(float2*)&w1fbf[e] = u.f2;
    } else if (bid < 1200) {                // w2f: 65536
        int e = ((bid - 1136) * 256 + t) * 4;
        float4 v = *(const float4*)&w2f[e];
        union { __bf16 h[4]; float2 f2; } u;
        u.h[0] = (__bf16)v.x; u.h[1] = (__bf16)v.y;
        u.h[2] = (__bf16)v.z; u.h[3] = (__bf16)v.w;
        *(float2*)&w2fbf[e] = u.f2;
    } else if (bid < 1456) {                // PE table: 65536 (l, j) pairs
        int p = (bid - 1200) * 256 + t;
        int l = p >> 6, jj = p & 63;
        float ang = (float)l * expf(-0.14391156831212787f * (float)jj) * 0.125f;
        peb[l * 128 + jj * 2]     = sinf(ang);
        peb[l * 128 + jj * 2 + 1] = cosf(ang);
    } else if (bid < 1488) {                // attn reversed rel tables: 8h x (2048 R0 | 2048 R1)
        int p = (bid - 1456) * 1024 + t * 4;
        #pragma unroll
        for (int j = 0; j < 4; j++) {
            int pe = p + j;
            int h = pe >> 12, i = pe & 4095;
            int half = i >> 11, ii = i & 2047;
            float v = 0.0f;
            if (half == 0) { if (ii <= 2046) v = rel[(size_t)(2046 - ii) * NHH + h]; }
            else           { if (ii <= 2045) v = rel[(size_t)(2045 - ii) * NHH + h]; }
            rtab[pe] = (__bf16)v;
        }
    } else {                                // fold BN1 into conv1 weights
        for (int o = t; o < DF; o += 256) {
            float A = g1[o] * INVS;
            #pragma unroll
            for (int tp = 0; tp < 7; tp++) w1A[o * 8 + tp] = c1w[o * 7 + tp] * A;
            w1A[o * 8 + 7] = 0.0f;
            b1A[o] = fmaf(c1b[o], A, bb1[o]);
        }
    }
}

// ---------- fused conv1+BN1+GELU -> bf16 MFMA conv2 GEMM -> BN2+GELU -> xsrc ----------
// 512 threads (8 waves), 32l x 128d tile, 32 chunks of 16 o, grid (32,16)
// conv math packed f32x2 over the c-pair (v_pk_fma_f32); breg[8] prefetched a phase ahead
__global__ __launch_bounds__(512, 4) void k_conv(
    const float* __restrict__ x,
    const float* __restrict__ w1A, const float* __restrict__ b1A,
    const __bf16* __restrict__ w2bf,
    const float* __restrict__ c2b, const float* __restrict__ g2,
    const float* __restrict__ bb2,
    float* __restrict__ xsrc)
{
    const int lt = blockIdx.x;      // 32 tiles of 32 l
    const int b  = blockIdx.y;      // 16
    const int t  = threadIdx.x;
    const int l0 = lt * 32;

    __shared__ float xs[CIN][40];
    __shared__ __align__(16) __bf16 Ab[2][32 * 256];

    for (int idx = t; idx < CIN * 38; idx += 512) {
        int c = idx / 38, i = idx % 38;
        int l = l0 - 3 + i;
        xs[c][i] = (l >= 0 && l < LL) ? x[(b * CIN + c) * LL + l] : 0.0f;
    }
    __syncthreads();

    const int lane = t & 63;
    const int wv   = t >> 6;                         // 0..7
    const int ogu  = __builtin_amdgcn_readfirstlane(wv); // wave-uniform o-subgroup
    const int cp   = lane & 7;
    const int lqi  = lane >> 3;                      // 0..7
    const int c0   = cp * 2;
    const int lq   = lqi * 4;

    f32x2 xw2[10];
    #pragma unroll
    for (int j = 0; j < 10; j++)
        xw2[j] = (f32x2){xs[c0][lq + j], xs[c0 + 1][lq + j]};

    const int l15 = lane & 15, kg = lane >> 4;

    f32x4 acc[2];
    acc[0] = (f32x4){0.f, 0.f, 0.f, 0.f};
    acc[1] = (f32x4){0.f, 0.f, 0.f, 0.f};

    bf16x8 breg[8];

#define BLOAD(CH) do { \
    _Pragma("unroll") \
    for (int kk = 0; kk < 8; kk++) \
        breg[kk] = *(const bf16x8*)&w2bf[ \
            (size_t)(wv * 16 + l15) * 8192 + (size_t)(CH) * 256 + kk * 32 + kg * 8]; \
} while (0)

#define CONV_CHUNK(BUF, CH) do { \
    _Pragma("unroll") \
    for (int j = 0; j < 2; j++) { \
        int o = (CH) * 16 + ogu * 2 + j; \
        f32x4 wA = *(const f32x4*)&w1A[o * 8]; \
        f32x4 wB = *(const f32x4*)&w1A[o * 8 + 4]; \
        float bias = b1A[o]; \
        int kcol = (ogu * 2 + j) * 16 + c0; \
        _Pragma("unroll") \
        for (int dl = 0; dl < 4; dl++) { \
            f32x2 s = (f32x2){bias, bias}; \
            s = s + xw2[dl]     * wA[0]; \
            s = s + xw2[dl + 1] * wA[1]; \
            s = s + xw2[dl + 2] * wA[2]; \
            s = s + xw2[dl + 3] * wA[3]; \
            s = s + xw2[dl + 4] * wB[0]; \
            s = s + xw2[dl + 5] * wB[1]; \
            s = s + xw2[dl + 6] * wB[2]; \
            f32x2 g = gelu2(s); \
            int l = lq + dl; \
            *(unsigned*)&Ab[BUF][l * 256 + (kcol ^ (SWZ(l) << 3))] = pkbf(g.x, g.y); \
        } \
    } \
} while (0)

#define MFMA_CHUNK(BUF) do { \
    _Pragma("unroll") \
    for (int kk = 0; kk < 8; kk++) { \
        int kb = kk * 32 + kg * 8; \
        _Pragma("unroll") \
        for (int mf = 0; mf < 2; mf++) { \
            int r = mf * 16 + l15; \
            bf16x8 af = *(const bf16x8*)&Ab[BUF][r * 256 + (kb ^ (SWZ(r) << 3))]; \
            acc[mf] = __builtin_amdgcn_mfma_f32_16x16x32_bf16(af, breg[kk], acc[mf], 0, 0, 0); \
        } \
    } \
} while (0)

    BLOAD(0);
    CONV_CHUNK(0, 0);
    __syncthreads();

    for (int ic = 0; ic < 30; ic += 2) {
        MFMA_CHUNK(0);
        BLOAD(ic + 1);
        CONV_CHUNK(1, ic + 1);
        __syncthreads();

        MFMA_CHUNK(1);
        BLOAD(ic + 2);
        CONV_CHUNK(0, ic + 2);
        __syncthreads();
    }
    MFMA_CHUNK(0);          // chunk 30
    BLOAD(31);
    CONV_CHUNK(1, 31);
    __syncthreads();
    MFMA_CHUNK(1);          // chunk 31

    // epilogue: BN2 + GELU  (C: col=lane&15 -> d-frag, row=(lane>>4)*4+r -> l)
    {
        int d = wv * 16 + l15;
        float A2 = g2[d] * INVS;
        float B2 = fmaf(c2b[d], A2, bb2[d]);
        #pragma unroll
        for (int mf = 0; mf < 2; mf++) {
            #pragma unroll
            for (int r = 0; r < 4; r++) {
                int l = l0 + mf * 16 + kg * 4 + r;
                xsrc[((size_t)b * LL + l) * DD + d] = gelu_t(fmaf(acc[mf][r], A2, B2));
            }
        }
    }
#undef BLOAD
#undef CONV_CHUNK
#undef MFMA_CHUNK
}

// ---------- qkv via MFMA: x_pos = xsrc + PE (bf16), out = x_pos @ W^T ----------
// 384 threads (6 waves): wave w covers 64 outputs of [q|k|v] (wq pre-scaled)
__global__ __launch_bounds__(384) void k_qkv(
    const float* __restrict__ xsrc, const float* __restrict__ peb,
    const __bf16* __restrict__ wallbf,
    __bf16* __restrict__ qo, __bf16* __restrict__ ko, __bf16* __restrict__ vo)
{
    const int lt = blockIdx.x, b = blockIdx.y;
    const int t = threadIdx.x;
    const int l0 = lt * 64;

    __shared__ __align__(16) __bf16 Xp[64 * 128];

    for (int e = t; e < 2048; e += 384) {
        int l = e >> 5, d0 = (e & 31) * 4;
        float4 xv = *(const float4*)&xsrc[((size_t)b * LL + l0 + l) * DD + d0];
        float4 pv = *(const float4*)&peb[(size_t)(l0 + l) * DD + d0];
        union { __bf16 h[4]; float2 f2; } u;
        u.h[0] = (__bf16)(xv.x + pv.x); u.h[1] = (__bf16)(xv.y + pv.y);
        u.h[2] = (__bf16)(xv.z + pv.z); u.h[3] = (__bf16)(xv.w + pv.w);
        *(float2*)&Xp[l * 128 + (d0 ^ (SWZ(l) << 3))] = u.f2;
    }
    __syncthreads();

    const int w = t >> 6, lane = t & 63;
    const int l15 = lane & 15, kg = lane >> 4;
    const int wsel = w >> 1, hb = w & 1;

    bf16x8 breg[16];
    #pragma unroll
    for (int nf = 0; nf < 4; nf++)
        #pragma unroll
        for (int kk = 0; kk < 4; kk++)
            breg[nf * 4 + kk] = *(const bf16x8*)&wallbf[
                (size_t)wsel * 16384 + (size_t)(hb * 64 + nf * 16 + l15) * 128 + kk * 32 + kg * 8];

    f32x4 acc[4][4];
    #pragma unroll
    for (int mf = 0; mf < 4; mf++)
        #pragma unroll
        for (int nf = 0; nf < 4; nf++) acc[mf][nf] = (f32x4){0.f, 0.f, 0.f, 0.f};

    #pragma unroll
    for (int kk = 0; kk < 4; kk++) {
        int kb = kk * 32 + kg * 8;
        bf16x8 af[4];
        #pragma unroll
        for (int mf = 0; mf < 4; mf++) {
            int r = mf * 16 + l15;
            af[mf] = *(const bf16x8*)&Xp[r * 128 + (kb ^ (SWZ(r) << 3))];
        }
        #pragma unroll
        for (int mf = 0; mf < 4; mf++)
            #pragma unroll
            for (int nf = 0; nf < 4; nf++)
                acc[mf][nf] = __builtin_amdgcn_mfma_f32_16x16x32_bf16(
                    af[mf], breg[nf * 4 + kk], acc[mf][nf], 0, 0, 0);
    }

    __bf16* op = (wsel == 0) ? qo : ((wsel == 1) ? ko : vo);
    #pragma unroll
    for (int mf = 0; mf < 4; mf++) {
        #pragma unroll
        for (int nf = 0; nf < 4; nf++) {
            int h = hb * 4 + nf;
            #pragma unroll
            for (int r = 0; r < 4; r++) {
                int l = l0 + mf * 16 + kg * 4 + r;
                op[(((size_t)b * NHH + h) * LL + l) * DHH + l15] = (__bf16)acc[mf][nf][r];
            }
        }
    }
}

// ---------- attention via MFMA: softmax(QK^T*s)@V + relbias@V  (flash, exp2 domain) ----------
__global__ __launch_bounds__(256) void k_attn(
    const __bf16* __restrict__ q, const __bf16* __restrict__ k,
    const __bf16* __restrict__ v, const __bf16* __restrict__ rtab,
    float* __restrict__ out)
{
    const int bh = blockIdx.x;           // 128
    const int qt = blockIdx.y;           // 8 tiles of 128 q
    const int h  = bh & 7;
    const int t  = threadIdx.x;
    const int w  = t >> 6, lane = t & 63;
    const int g  = lane >> 4, qi = lane & 15;
    const int xq = (qi & 7) << 3;
    const int qbase = qt * 128 + w * 32;

    __shared__ __align__(16) __bf16 lds[16384];
    __bf16* Vl = lds;                    // 4096
    __bf16* Pw = lds + 4096 + w * 2048;  // per-wave 2048
    __bf16* R0 = lds + 12288;            // 2048
    __bf16* R1 = lds + 14336;            // 2048

    // copy this head's precomputed reversed tables (R0|R1 contiguous, 4096 bf16)
    {
        const __bf16* src = rtab + (size_t)h * 4096;
        #pragma unroll
        for (int i = 0; i < 2; i++) {
            int e = (i * 256 + t) * 8;
            *(bf16x8*)&lds[12288 + e] = *(const bf16x8*)&src[e];
        }
    }

    bf16x8 qf[2];
    {
        union { unsigned u[4]; bf16x8 v8; } uz;
        uz.u[0] = uz.u[1] = uz.u[2] = uz.u[3] = 0u;
        #pragma unroll
        for (int n = 0; n < 2; n++) {
            qf[n] = uz.v8;
            if (g < 2)
                qf[n] = *(const bf16x8*)&q[((size_t)bh * LL + qbase + n * 16 + qi) * DHH + g * 8];
        }
    }

    f32x4 accp[2], accb[2];
    #pragma unroll
    for (int n = 0; n < 2; n++) {
        accp[n] = (f32x4){0.f, 0.f, 0.f, 0.f};
        accb[n] = (f32x4){0.f, 0.f, 0.f, 0.f};
    }
    float mrun[2] = {-INFINITY, -INFINITY};
    float lrun[2] = {0.f, 0.f};

    const f32x4 zero4 = (f32x4){0.f, 0.f, 0.f, 0.f};

// S is in log2 domain (q pre-scaled by 1/sqrt(128)*log2e) -> bare v_exp_f32
#define PROC_N(Sn, n) do { \
    float mx = Sn[0][0]; \
    _Pragma("unroll") \
    for (int f = 0; f < 8; f++) { \
        _Pragma("unroll") \
        for (int r = 0; r < 4; r++) if (f || r) mx = fmaxf(mx, Sn[f][r]); } \
    mx = fmaxf(mx, __shfl_xor(mx, 16, 64)); \
    mx = fmaxf(mx, __shfl_xor(mx, 32, 64)); \
    float mnew = fmaxf(mrun[n], mx); \
    float sf = __builtin_amdgcn_exp2f(mrun[n] - mnew); \
    mrun[n] = mnew; \
    lrun[n] *= sf; \
    accp[n][0] *= sf; accp[n][1] *= sf; accp[n][2] *= sf; accp[n][3] *= sf; \
    float ls = 0.f; \
    _Pragma("unroll") \
    for (int f = 0; f < 8; f++) { \
        float p0 = __builtin_amdgcn_exp2f(Sn[f][0] - mnew); \
        float p1 = __builtin_amdgcn_exp2f(Sn[f][1] - mnew); \
        float p2 = __builtin_amdgcn_exp2f(Sn[f][2] - mnew); \
        float p3 = __builtin_amdgcn_exp2f(Sn[f][3] - mnew); \
        ls += (p0 + p1) + (p2 + p3); \
        unsigned* pp = (unsigned*)(Pw + (qi * 128 + ((f * 16 + g * 4) ^ xq))); \
        pp[0] = pkbf(p0, p1); pp[1] = pkbf(p2, p3); \
    } \
    ls += __shfl_xor(ls, 16, 64); ls += __shfl_xor(ls, 32, 64); \
    lrun[n] += ls; \
    int qoff = 1023 - (qbase + (n) * 16 + qi) + k0; \
    _Pragma("unroll") \
    for (int c = 0; c < 4; c++) { \
        bf16x8 vf = *(const bf16x8*)&Vbuf[qi * 128 + ((c * 32 + g * 8) ^ xq)]; \
        bf16x8 pf = *(const bf16x8*)&Pw[qi * 128 + ((c * 32 + g * 8) ^ xq)]; \
        int idx = qoff + c * 32 + 8 * g; \
        const unsigned* tb = (const unsigned*)((idx & 1) ? R1 : R0); \
        unsigned s_ = (unsigned)idx >> 1; \
        union { unsigned u[4]; bf16x8 v8; } bu; \
        bu.u[0] = tb[s_]; bu.u[1] = tb[s_ + 1]; \
        bu.u[2] = tb[s_ + 2]; bu.u[3] = tb[s_ + 3]; \
        accp[n] = __builtin_amdgcn_mfma_f32_16x16x32_bf16(vf, pf, accp[n], 0, 0, 0); \
        accb[n] = __builtin_amdgcn_mfma_f32_16x16x32_bf16(vf, bu.v8, accb[n], 0, 0, 0); \
    } \
} while (0)

    for (int kt = 0; kt < 8; kt++) {
        const int k0 = kt * 128;
        {
            int kr = t >> 1, d0 = (t & 1) * 8;
            bf16x8 b8 = *(const bf16x8*)&v[((size_t)bh * LL + k0 + kr) * DHH + d0];
            __bf16* dst = Vl + (kt & 1) * 2048;
            #pragma unroll
            for (int i = 0; i < 8; i++) {
                int d = d0 + i;
                dst[d * 128 + (kr ^ ((d & 7) << 3))] = b8[i];
            }
        }
        __syncthreads();
        const __bf16* Vbuf = Vl + (kt & 1) * 2048;

        f32x4 S0[8], S1[8];
        #pragma unroll
        for (int f = 0; f < 8; f++) {
            bf16x8 kf = *(const bf16x8*)&k[((size_t)bh * LL + k0 + f * 16 + qi) * DHH + (g & 1) * 8];
            S0[f] = __builtin_amdgcn_mfma_f32_16x16x32_bf16(kf, qf[0], zero4, 0, 0, 0);
            S1[f] = __builtin_amdgcn_mfma_f32_16x16x32_bf16(kf, qf[1], zero4, 0, 0, 0);
        }

        PROC_N(S0, 0);
        PROC_N(S1, 1);
    }
#undef PROC_N

    #pragma unroll
    for (int n = 0; n < 2; n++) {
        float inv = 1.0f / lrun[n];
        float4 o;
        o.x = accp[n][0] * inv + accb[n][0];
        o.y = accp[n][1] * inv + accb[n][1];
        o.z = accp[n][2] * inv + accb[n][2];
        o.w = accp[n][3] * inv + accb[n][3];
        *(float4*)&out[((size_t)bh * LL + qbase + n * 16 + qi) * DHH + g * 4] = o;
    }
}

// ---------- LN(attn_out) ; att = LN(x_src + .) ----------
__global__ __launch_bounds__(256) void k_ln(
    const float* __restrict__ ao,  const float* __restrict__ xsrc,
    const float* __restrict__ lag, const float* __restrict__ lab,
    const float* __restrict__ l1g, const float* __restrict__ l1b,
    float* __restrict__ att)
{
    const int lt = blockIdx.x, b = blockIdx.y;
    const int t = threadIdx.x;
    const int l0 = lt * 64;
    __shared__ float tile[64][132];

    #pragma unroll
    for (int u = 0; u < 4; u++) {
        int cid = u * 256 + t;
        int hh = cid >> 7, rem = cid & 127;
        int l = rem >> 1, dh0 = (rem & 1) * 8;
        const float* src = &ao[(((size_t)b * NHH + hh) * LL + l0 + l) * DHH + dh0];
        float4 a0 = *(const float4*)src;
        float4 a1 = *(const float4*)(src + 4);
        *(float4*)&tile[l][hh * 16 + dh0]     = a0;
        *(float4*)&tile[l][hh * 16 + dh0 + 4] = a1;
    }
    __syncthreads();

    const int wid = t >> 6, lane = t & 63;
    float2 ga  = *(const float2*)&lag[lane * 2];
    float2 ba  = *(const float2*)&lab[lane * 2];
    float2 g1v = *(const float2*)&l1g[lane * 2];
    float2 b1v = *(const float2*)&l1b[lane * 2];

    for (int rr = 0; rr < 16; rr++) {
        int r = wid * 16 + rr;
        float2 vv = *(const float2*)&tile[r][lane * 2];
        float s = vv.x + vv.y, s2 = vv.x * vv.x + vv.y * vv.y;
        #pragma unroll
        for (int m = 1; m < 64; m <<= 1) { s += __shfl_xor(s, m, 64); s2 += __shfl_xor(s2, m, 64); }
        float mu = s * (1.f / 128.f);
        float var = s2 * (1.f / 128.f) - mu * mu;
        float rs = rsqrtf(var + 1e-5f);
        float o0 = (vv.x - mu) * rs * ga.x + ba.x;
        float o1 = (vv.y - mu) * rs * ga.y + ba.y;
        float2 xv = *(const float2*)&xsrc[((size_t)b * LL + l0 + r) * DD + lane * 2];
        float t0 = xv.x + o0, t1 = xv.y + o1;
        s = t0 + t1; s2 = t0 * t0 + t1 * t1;
        #pragma unroll
        for (int m = 1; m < 64; m <<= 1) { s += __shfl_xor(s, m, 64); s2 += __shfl_xor(s2, m, 64); }
        mu = s * (1.f / 128.f);
        var = s2 * (1.f / 128.f) - mu * mu;
        rs = rsqrtf(var + 1e-5f);
        float a0 = (t0 - mu) * rs * g1v.x + b1v.x;
        float a1 = (t1 - mu) * rs * g1v.y + b1v.y;
        float2 o = {a0, a1};
        *(float2*)&att[((size_t)b * LL + l0 + r) * DD + lane * 2] = o;
    }
}

// ---------- ff1 = relu(att @ w1^T + b1) -> bf16, MFMA ----------
__global__ __launch_bounds__(512) void k_ff1(
    const float* __restrict__ att, const __bf16* __restrict__ w1fbf,
    const float* __restrict__ b1f, __bf16* __restrict__ ff1b)
{
    const int lt = blockIdx.x, b = blockIdx.y;
    const int t = threadIdx.x;
    const int l0 = lt * 64;

    __shared__ __align__(16) __bf16 Ax[64 * 128];

    #pragma unroll
    for (int it = 0; it < 4; it++) {
        int e = it * 512 + t;
        int l = e >> 5, d0 = (e & 31) * 4;
        float4 xv = *(const float4*)&att[((size_t)b * LL + l0 + l) * DD + d0];
        union { __bf16 h[4]; float2 f2; } u;
        u.h[0] = (__bf16)xv.x; u.h[1] = (__bf16)xv.y;
        u.h[2] = (__bf16)xv.z; u.h[3] = (__bf16)xv.w;
        *(float2*)&Ax[l * 128 + (d0 ^ (SWZ(l) << 3))] = u.f2;
    }
    __syncthreads();

    const int w = t >> 6, lane = t & 63;
    const int l15 = lane & 15, kg = lane >> 4;

    bf16x8 breg[16];
    #pragma unroll
    for (int nf = 0; nf < 4; nf++)
        #pragma unroll
        for (int kk = 0; kk < 4; kk++)
            breg[nf * 4 + kk] = *(const bf16x8*)&w1fbf[
                (size_t)(w * 64 + nf * 16 + l15) * 128 + kk * 32 + kg * 8];

    f32x4 acc[4][4];
    #pragma unroll
    for (int mf = 0; mf < 4; mf++)
        #pragma unroll
        for (int nf = 0; nf < 4; nf++) acc[mf][nf] = (f32x4){0.f, 0.f, 0.f, 0.f};

    #pragma unroll
    for (int kk = 0; kk < 4; kk++) {
        int kb = kk * 32 + kg * 8;
        bf16x8 af[4];
        #pragma unroll
        for (int mf = 0; mf < 4; mf++) {
            int r = mf * 16 + l15;
            af[mf] = *(const bf16x8*)&Ax[r * 128 + (kb ^ (SWZ(r) << 3))];
        }
        #pragma unroll
        for (int mf = 0; mf < 4; mf++)
            #pragma unroll
            for (int nf = 0; nf < 4; nf++)
                acc[mf][nf] = __builtin_amdgcn_mfma_f32_16x16x32_bf16(
                    af[mf], breg[nf * 4 + kk], acc[mf][nf], 0, 0, 0);
    }

    #pragma unroll
    for (int nf = 0; nf < 4; nf++) {
        int n = w * 64 + nf * 16 + l15;
        float bias = b1f[n];
        #pragma unroll
        for (int mf = 0; mf < 4; mf++) {
            #pragma unroll
            for (int r = 0; r < 4; r++) {
                int l = l0 + mf * 16 + kg * 4 + r;
                float vv = fmaxf(acc[mf][nf][r] + bias, 0.0f);
                ff1b[((size_t)b * LL + l) * DF + n] = (__bf16)vv;
            }
        }
    }
}

// ---------- ff2 (MFMA, K=512) + bias + residual + LN2 + transpose-store ----------
__global__ __launch_bounds__(512) void k_ff2(
    const __bf16* __restrict__ ff1b, const __bf16* __restrict__ w2fbf,
    const float* __restrict__ b2f, const float* __restrict__ att,
    const float* __restrict__ l2g, const float* __restrict__ l2b,
    float* __restrict__ y)
{
    const int lt = blockIdx.x, b = blockIdx.y;
    const int t = threadIdx.x;
    const int l0 = lt * 64;

    __shared__ __align__(16) __bf16 Ax[64 * 512];   // 64KB; reused as yl after GEMM
    float* yl = (float*)Ax;                          // [64][132] overlay

    #pragma unroll
    for (int it = 0; it < 8; it++) {
        int g8 = it * 512 + t;                       // 4096 granules of 8
        int l = g8 >> 6, c8 = g8 & 63;
        bf16x8 v8 = *(const bf16x8*)&ff1b[((size_t)b * LL + l0 + l) * DF + c8 * 8];
        *(bf16x8*)&Ax[l * 512 + ((c8 * 8) ^ (SWZ(l) << 3))] = v8;
    }
    __syncthreads();

    const int w = t >> 6, lane = t & 63;
    const int l15 = lane & 15, kg = lane >> 4;
    const int d = w * 16 + l15;

    bf16x8 breg[16];
    #pragma unroll
    for (int kk = 0; kk < 16; kk++)
        breg[kk] = *(const bf16x8*)&w2fbf[(size_t)d * DF + kk * 32 + kg * 8];

    f32x4 acc[4];
    #pragma unroll
    for (int mf = 0; mf < 4; mf++) acc[mf] = (f32x4){0.f, 0.f, 0.f, 0.f};

    #pragma unroll
    for (int kk = 0; kk < 16; kk++) {
        int kb = kk * 32 + kg * 8;
        #pragma unroll
        for (int mf = 0; mf < 4; mf++) {
            int r = mf * 16 + l15;
            bf16x8 af = *(const bf16x8*)&Ax[r * 512 + (kb ^ (SWZ(r) << 3))];
            acc[mf] = __builtin_amdgcn_mfma_f32_16x16x32_bf16(af, breg[kk], acc[mf], 0, 0, 0);
        }
    }
    __syncthreads();   // Ax reads done; overlay as yl

    {
        float bias = b2f[d];
        #pragma unroll
        for (int mf = 0; mf < 4; mf++) {
            #pragma unroll
            for (int r = 0; r < 4; r++) {
                int l = mf * 16 + kg * 4 + r;
                float res = att[((size_t)b * LL + l0 + l) * DD + d];
                yl[l * 132 + d] = acc[mf][r] + bias + res;
            }
        }
    }
    __syncthreads();

    const int wid = t >> 6;
    float2 gv = *(const float2*)&l2g[lane * 2];
    float2 bv = *(const float2*)&l2b[lane * 2];
    for (int rr = 0; rr < 8; rr++) {
        int r = wid * 8 + rr;
        float2 vv = *(const float2*)&yl[r * 132 + lane * 2];
        float s = vv.x + vv.y, s2 = vv.x * vv.x + vv.y * vv.y;
        #pragma unroll
        for (int m = 1; m < 64; m <<= 1) { s += __shfl_xor(s, m, 64); s2 += __shfl_xor(s2, m, 64); }
        float mu = s * (1.f / 128.f);
        float var = s2 * (1.f / 128.f) - mu * mu;
        float rs = rsqrtf(var + 1e-5f);
        float o0 = (vv.x - mu) * rs * gv.x + bv.x;
        float o1 = (vv.y - mu) * rs * gv.y + bv.y;
        yl[r * 132 + lane * 2]     = o0;
        yl[r * 132 + lane * 2 + 1] = o1;
    }
    __syncthreads();

    {
        int dd = t >> 2, lh = (t & 3) * 16;
        #pragma unroll
        for (int i0 = 0; i0 < 16; i0 += 4) {
            float4 o = { yl[(lh + i0 + 0) * 132 + dd], yl[(lh + i0 + 1) * 132 + dd],
                         yl[(lh + i0 + 2) * 132 + dd], yl[(lh + i0 + 3) * 132 + dd] };
            *(float4*)&y[(size_t)b * DD * LL + (size_t)dd * LL + l0 + lh + i0] = o;
        }
    }
}

extern "C" void kernel_launch(void* const* d_in, const int* in_sizes, int n_in,
                              void* d_out, int out_size, void* d_ws, size_t ws_size,
                              hipStream_t stream)
{
    const float* x   = (const float*)d_in[0];
    const float* c1w = (const float*)d_in[1];
    const float* c1b = (const float*)d_in[2];
    const float* g1  = (const float*)d_in[3];
    const float* bb1 = (const float*)d_in[4];
    const float* c2w = (const float*)d_in[5];
    const float* c2b = (const float*)d_in[6];
    const float* g2  = (const float*)d_in[7];
    const float* bb2 = (const float*)d_in[8];
    const float* wq  = (const float*)d_in[9];
    const float* wk  = (const float*)d_in[10];
    const float* wv  = (const float*)d_in[11];
    const float* rel = (const float*)d_in[12];
    const float* lag = (const float*)d_in[13];
    const float* lab = (const float*)d_in[14];
    const float* l1g = (const float*)d_in[15];
    const float* l1b = (const float*)d_in[16];
    const float* l2g = (const float*)d_in[17];
    const float* l2b = (const float*)d_in[18];
    const float* w1f = (const float*)d_in[19];
    const float* b1f = (const float*)d_in[20];
    const float* w2f = (const float*)d_in[21];
    const float* b2f = (const float*)d_in[22];

    char* W = (char*)d_ws;
    const size_t MB = 1ull << 20;
    float*  xsrc   = (float*)(W);
    float*  abuf   = (float*)(W + 8 * MB);
    float*  attb   = (float*)(W + 16 * MB);
    __bf16* qbuf   = (__bf16*)(W + 24 * MB);
    __bf16* kbuf   = (__bf16*)(W + 28 * MB);
    __bf16* vbuf   = (__bf16*)(W + 32 * MB);
    __bf16* ff1b   = (__bf16*)(W + 36 * MB);
    __bf16* w2bf   = (__bf16*)(W + 52 * MB);
    __bf16* wallbf = (__bf16*)(W + 54 * MB);
    __bf16* w1fbf  = (__bf16*)(W + 54 * MB + 128 * 1024);
    __bf16* w2fbf  = (__bf16*)(W + 54 * MB + 256 * 1024);
    float*  peb    = (float*)(W + 54 * MB + 384 * 1024);
    float*  w1A    = (float*)(W + 54 * MB + 896 * 1024);
    float*  b1A    = (float*)(W + 54 * MB + 912 * 1024);
    __bf16* rtab   = (__bf16*)(W + 54 * MB + 928 * 1024);   // 8 heads x 4096 bf16 = 64KB

    k_prep<<<dim3(1489), dim3(256), 0, stream>>>(
        c2w, wq, wk, wv, w1f, w2f, c1w, c1b, g1, bb1, rel,
        w2bf, wallbf, w1fbf, w2fbf, peb, w1A, b1A, rtab);
    k_conv<<<dim3(32, 16), dim3(512), 0, stream>>>(x, w1A, b1A, w2bf, c2b, g2, bb2, xsrc);
    k_qkv<<<dim3(16, 16), dim3(384), 0, stream>>>(xsrc, peb, wallbf, qbuf, kbuf, vbuf);
    k_attn<<<dim3(128, 8), dim3(256), 0, stream>>>(qbuf, kbuf, vbuf, rtab, abuf);
    k_ln<<<dim3(16, 16), dim3(256), 0, stream>>>(abuf, xsrc, lag, lab, l1g, l1b, attb);
    k_ff1<<<dim3(16, 16), dim3(512), 0, stream>>>(attb, w1fbf, b1f, ff1b);
    k_ff2<<<dim3(16, 16), dim3(512), 0, stream>>>(ff1b, w2fbf, b2f, attb, l2g, l2b, (float*)d_out);
}

// Round 14
// 224.412 us; speedup vs baseline: 1.5657x; 1.0349x over previous
//
#include <hip/hip_runtime.h>
#include <math.h>

#define BB   16
#define CIN  16
#define LL   1024
#define DD   128
#define NHH  8
#define DHH  16
#define DF   512

#define INVS 0.9999950000374998f   // 1/sqrt(1+1e-5)
#define QSCALE2 0.12751743f        // (1/sqrt(128)) * log2(e)  -> softmax in exp2 domain

typedef __attribute__((ext_vector_type(2))) float f32x2;
typedef __attribute__((ext_vector_type(4))) float f32x4;
typedef __attribute__((ext_vector_type(8))) __bf16 bf16x8;

// tanh-form GELU: v*sigmoid(1.59577*(v+0.044715 v^3)), |err vs erf| <= ~4e-4
__device__ __forceinline__ float gelu_t(float v) {
    float u = v * v;
    float a = v * fmaf(-0.07135481627f, u, -1.5957691216f);
    float e = __expf(a);
    return v * __builtin_amdgcn_rcpf(1.0f + e);
}

// packed-f32 gelu (exp2-domain constants; same function, c-pair vectorized)
__device__ __forceinline__ f32x2 gelu2(f32x2 v) {
    f32x2 u = v * v;
    f32x2 a = v * (u * (-0.10294425f) + (-2.3022082f));   // -z/ln2
    f32x2 e;
    e.x = __builtin_amdgcn_exp2f(a.x);
    e.y = __builtin_amdgcn_exp2f(a.y);
    f32x2 r;
    r.x = __builtin_amdgcn_rcpf(1.0f + e.x);
    r.y = __builtin_amdgcn_rcpf(1.0f + e.y);
    return v * r;
}

__device__ __forceinline__ unsigned pkbf(float a, float b) {
    union { __bf16 h[2]; unsigned u; } z;
    z.h[0] = (__bf16)a; z.h[1] = (__bf16)b;
    return z.u;
}

#define SWZ(l) ((((l) & 7) ^ (((l) >> 2) & 6)))

// ---------- one prep kernel: weight conversions + PE table + attn rel tables ----------
__global__ __launch_bounds__(256) void k_prep(
    const float* __restrict__ c2w,
    const float* __restrict__ wq, const float* __restrict__ wk,
    const float* __restrict__ wv,
    const float* __restrict__ w1f, const float* __restrict__ w2f,
    const float* __restrict__ c1w, const float* __restrict__ c1b,
    const float* __restrict__ g1,  const float* __restrict__ bb1,
    const float* __restrict__ rel,
    __bf16* __restrict__ w2bf,  __bf16* __restrict__ wallbf,
    __bf16* __restrict__ w1fbf, __bf16* __restrict__ w2fbf,
    float* __restrict__ peb, float* __restrict__ w1A, float* __restrict__ b1A,
    __bf16* __restrict__ rtab)
{
    const int bid = blockIdx.x;
    const int t = threadIdx.x;
    if (bid < 1024) {                       // w2: 1M elems
        int i = (bid * 256 + t) * 4;
        float4 v = *(const float4*)&c2w[i];
        union { __bf16 h[4]; float2 f2; } u;
        u.h[0] = (__bf16)v.x; u.h[1] = (__bf16)v.y;
        u.h[2] = (__bf16)v.z; u.h[3] = (__bf16)v.w;
        *(float2*)&w2bf[i] = u.f2;
    } else if (bid < 1072) {                // wq|wk|wv: 3*16384, wq pre-scaled (incl log2e)
        int e = ((bid - 1024) * 256 + t) * 4;
        int sel = e >> 14, r = e & 16383;
        const float* src = (sel == 0) ? wq : ((sel == 1) ? wk : wv);
        float sc = (sel == 0) ? QSCALE2 : 1.0f;
        float4 v = *(const float4*)&src[r];
        union { __bf16 h[4]; float2 f2; } u;
        u.h[0] = (__bf16)(v.x * sc); u.h[1] = (__bf16)(v.y * sc);
        u.h[2] = (__bf16)(v.z * sc); u.h[3] = (__bf16)(v.w * sc);
        *(float2*)&wallbf[e] = u.f2;
    } else if (bid < 1136) {                // w1f: 65536
        int e = ((bid - 1072) * 256 + t) * 4;
        float4 v = *(const float4*)&w1f[e];
        union { __bf16 h[4]; float2 f2; } u;
        u.h[0] = (__bf16)v.x; u.h[1] = (__bf16)v.y;
        u.h[2] = (__bf16)v.z; u.h[3] = (__bf16)v.w;
        *(float2*)&w1fbf[e] = u.f2;
    } else if (bid < 1200) {                // w2f: 65536
        int e = ((bid - 1136) * 256 + t) * 4;
        float4 v = *(const float4*)&w2f[e];
        union { __bf16 h[4]; float2 f2; } u;
        u.h[0] = (__bf16)v.x; u.h[1] = (__bf16)v.y;
        u.h[2] = (__bf16)v.z; u.h[3] = (__bf16)v.w;
        *(float2*)&w2fbf[e] = u.f2;
    } else if (bid < 1456) {                // PE table: 65536 (l, j) pairs
        int p = (bid - 1200) * 256 + t;
        int l = p >> 6, jj = p & 63;
        float ang = (float)l * expf(-0.14391156831212787f * (float)jj) * 0.125f;
        peb[l * 128 + jj * 2]     = sinf(ang);
        peb[l * 128 + jj * 2 + 1] = cosf(ang);
    } else if (bid < 1488) {                // attn reversed rel tables: 8h x (2048 R0 | 2048 R1)
        int p = (bid - 1456) * 1024 + t * 4;
        #pragma unroll
        for (int j = 0; j < 4; j++) {
            int pe = p + j;
            int h = pe >> 12, i = pe & 4095;
            int half = i >> 11, ii = i & 2047;
            float v = 0.0f;
            if (half == 0) { if (ii <= 2046) v = rel[(size_t)(2046 - ii) * NHH + h]; }
            else           { if (ii <= 2045) v = rel[(size_t)(2045 - ii) * NHH + h]; }
            rtab[pe] = (__bf16)v;
        }
    } else {                                // fold BN1 into conv1 weights
        for (int o = t; o < DF; o += 256) {
            float A = g1[o] * INVS;
            #pragma unroll
            for (int tp = 0; tp < 7; tp++) w1A[o * 8 + tp] = c1w[o * 7 + tp] * A;
            w1A[o * 8 + 7] = 0.0f;
            b1A[o] = fmaf(c1b[o], A, bb1[o]);
        }
    }
}

// ---------- fused conv1+BN1+GELU -> bf16 MFMA conv2 GEMM -> BN2+GELU -> xsrc ----------
// 512 threads (8 waves), 32l x 128d tile, 32 chunks of 16 o, grid (32,16)
// conv math packed f32x2 over the c-pair (v_pk_fma_f32); breg[8] prefetched a phase ahead
__global__ __launch_bounds__(512, 4) void k_conv(
    const float* __restrict__ x,
    const float* __restrict__ w1A, const float* __restrict__ b1A,
    const __bf16* __restrict__ w2bf,
    const float* __restrict__ c2b, const float* __restrict__ g2,
    const float* __restrict__ bb2,
    float* __restrict__ xsrc)
{
    const int lt = blockIdx.x;      // 32 tiles of 32 l
    const int b  = blockIdx.y;      // 16
    const int t  = threadIdx.x;
    const int l0 = lt * 32;

    __shared__ float xs[CIN][40];
    __shared__ __align__(16) __bf16 Ab[2][32 * 256];

    for (int idx = t; idx < CIN * 38; idx += 512) {
        int c = idx / 38, i = idx % 38;
        int l = l0 - 3 + i;
        xs[c][i] = (l >= 0 && l < LL) ? x[(b * CIN + c) * LL + l] : 0.0f;
    }
    __syncthreads();

    const int lane = t & 63;
    const int wv   = t >> 6;                         // 0..7
    const int ogu  = __builtin_amdgcn_readfirstlane(wv); // wave-uniform o-subgroup
    const int cp   = lane & 7;
    const int lqi  = lane >> 3;                      // 0..7
    const int c0   = cp * 2;
    const int lq   = lqi * 4;

    f32x2 xw2[10];
    #pragma unroll
    for (int j = 0; j < 10; j++)
        xw2[j] = (f32x2){xs[c0][lq + j], xs[c0 + 1][lq + j]};

    const int l15 = lane & 15, kg = lane >> 4;

    f32x4 acc[2];
    acc[0] = (f32x4){0.f, 0.f, 0.f, 0.f};
    acc[1] = (f32x4){0.f, 0.f, 0.f, 0.f};

    bf16x8 breg[8];

#define BLOAD(CH) do { \
    _Pragma("unroll") \
    for (int kk = 0; kk < 8; kk++) \
        breg[kk] = *(const bf16x8*)&w2bf[ \
            (size_t)(wv * 16 + l15) * 8192 + (size_t)(CH) * 256 + kk * 32 + kg * 8]; \
} while (0)

#define CONV_CHUNK(BUF, CH) do { \
    _Pragma("unroll") \
    for (int j = 0; j < 2; j++) { \
        int o = (CH) * 16 + ogu * 2 + j; \
        f32x4 wA = *(const f32x4*)&w1A[o * 8]; \
        f32x4 wB = *(const f32x4*)&w1A[o * 8 + 4]; \
        float bias = b1A[o]; \
        int kcol = (ogu * 2 + j) * 16 + c0; \
        _Pragma("unroll") \
        for (int dl = 0; dl < 4; dl++) { \
            f32x2 s = (f32x2){bias, bias}; \
            s = s + xw2[dl]     * wA[0]; \
            s = s + xw2[dl + 1] * wA[1]; \
            s = s + xw2[dl + 2] * wA[2]; \
            s = s + xw2[dl + 3] * wA[3]; \
            s = s + xw2[dl + 4] * wB[0]; \
            s = s + xw2[dl + 5] * wB[1]; \
            s = s + xw2[dl + 6] * wB[2]; \
            f32x2 g = gelu2(s); \
            int l = lq + dl; \
            *(unsigned*)&Ab[BUF][l * 256 + (kcol ^ (SWZ(l) << 3))] = pkbf(g.x, g.y); \
        } \
    } \
} while (0)

#define MFMA_CHUNK(BUF) do { \
    _Pragma("unroll") \
    for (int kk = 0; kk < 8; kk++) { \
        int kb = kk * 32 + kg * 8; \
        _Pragma("unroll") \
        for (int mf = 0; mf < 2; mf++) { \
            int r = mf * 16 + l15; \
            bf16x8 af = *(const bf16x8*)&Ab[BUF][r * 256 + (kb ^ (SWZ(r) << 3))]; \
            acc[mf] = __builtin_amdgcn_mfma_f32_16x16x32_bf16(af, breg[kk], acc[mf], 0, 0, 0); \
        } \
    } \
} while (0)

    BLOAD(0);
    CONV_CHUNK(0, 0);
    __syncthreads();

    for (int ic = 0; ic < 30; ic += 2) {
        MFMA_CHUNK(0);
        BLOAD(ic + 1);
        CONV_CHUNK(1, ic + 1);
        __syncthreads();

        MFMA_CHUNK(1);
        BLOAD(ic + 2);
        CONV_CHUNK(0, ic + 2);
        __syncthreads();
    }
    MFMA_CHUNK(0);          // chunk 30
    BLOAD(31);
    CONV_CHUNK(1, 31);
    __syncthreads();
    MFMA_CHUNK(1);          // chunk 31

    // epilogue: BN2 + GELU  (C: col=lane&15 -> d-frag, row=(lane>>4)*4+r -> l)
    {
        int d = wv * 16 + l15;
        float A2 = g2[d] * INVS;
        float B2 = fmaf(c2b[d], A2, bb2[d]);
        #pragma unroll
        for (int mf = 0; mf < 2; mf++) {
            #pragma unroll
            for (int r = 0; r < 4; r++) {
                int l = l0 + mf * 16 + kg * 4 + r;
                xsrc[((size_t)b * LL + l) * DD + d] = gelu_t(fmaf(acc[mf][r], A2, B2));
            }
        }
    }
#undef BLOAD
#undef CONV_CHUNK
#undef MFMA_CHUNK
}

// ---------- qkv via MFMA: x_pos = xsrc + PE (bf16), out = x_pos @ W^T ----------
// 384 threads (6 waves): wave w covers 64 outputs of [q|k|v] (wq pre-scaled)
__global__ __launch_bounds__(384) void k_qkv(
    const float* __restrict__ xsrc, const float* __restrict__ peb,
    const __bf16* __restrict__ wallbf,
    __bf16* __restrict__ qo, __bf16* __restrict__ ko, __bf16* __restrict__ vo)
{
    const int lt = blockIdx.x, b = blockIdx.y;
    const int t = threadIdx.x;
    const int l0 = lt * 64;

    __shared__ __align__(16) __bf16 Xp[64 * 128];

    for (int e = t; e < 2048; e += 384) {
        int l = e >> 5, d0 = (e & 31) * 4;
        float4 xv = *(const float4*)&xsrc[((size_t)b * LL + l0 + l) * DD + d0];
        float4 pv = *(const float4*)&peb[(size_t)(l0 + l) * DD + d0];
        union { __bf16 h[4]; float2 f2; } u;
        u.h[0] = (__bf16)(xv.x + pv.x); u.h[1] = (__bf16)(xv.y + pv.y);
        u.h[2] = (__bf16)(xv.z + pv.z); u.h[3] = (__bf16)(xv.w + pv.w);
        *(float2*)&Xp[l * 128 + (d0 ^ (SWZ(l) << 3))] = u.f2;
    }
    __syncthreads();

    const int w = t >> 6, lane = t & 63;
    const int l15 = lane & 15, kg = lane >> 4;
    const int wsel = w >> 1, hb = w & 1;

    bf16x8 breg[16];
    #pragma unroll
    for (int nf = 0; nf < 4; nf++)
        #pragma unroll
        for (int kk = 0; kk < 4; kk++)
            breg[nf * 4 + kk] = *(const bf16x8*)&wallbf[
                (size_t)wsel * 16384 + (size_t)(hb * 64 + nf * 16 + l15) * 128 + kk * 32 + kg * 8];

    f32x4 acc[4][4];
    #pragma unroll
    for (int mf = 0; mf < 4; mf++)
        #pragma unroll
        for (int nf = 0; nf < 4; nf++) acc[mf][nf] = (f32x4){0.f, 0.f, 0.f, 0.f};

    #pragma unroll
    for (int kk = 0; kk < 4; kk++) {
        int kb = kk * 32 + kg * 8;
        bf16x8 af[4];
        #pragma unroll
        for (int mf = 0; mf < 4; mf++) {
            int r = mf * 16 + l15;
            af[mf] = *(const bf16x8*)&Xp[r * 128 + (kb ^ (SWZ(r) << 3))];
        }
        #pragma unroll
        for (int mf = 0; mf < 4; mf++)
            #pragma unroll
            for (int nf = 0; nf < 4; nf++)
                acc[mf][nf] = __builtin_amdgcn_mfma_f32_16x16x32_bf16(
                    af[mf], breg[nf * 4 + kk], acc[mf][nf], 0, 0, 0);
    }

    __bf16* op = (wsel == 0) ? qo : ((wsel == 1) ? ko : vo);
    #pragma unroll
    for (int mf = 0; mf < 4; mf++) {
        #pragma unroll
        for (int nf = 0; nf < 4; nf++) {
            int h = hb * 4 + nf;
            #pragma unroll
            for (int r = 0; r < 4; r++) {
                int l = l0 + mf * 16 + kg * 4 + r;
                op[(((size_t)b * NHH + h) * LL + l) * DHH + l15] = (__bf16)acc[mf][nf][r];
            }
        }
    }
}

// ---------- attention via MFMA: softmax(QK^T*s)@V + relbias@V  (flash, exp2 domain) ----------
__global__ __launch_bounds__(256) void k_attn(
    const __bf16* __restrict__ q, const __bf16* __restrict__ k,
    const __bf16* __restrict__ v, const __bf16* __restrict__ rtab,
    float* __restrict__ out)
{
    const int bh = blockIdx.x;           // 128
    const int qt = blockIdx.y;           // 8 tiles of 128 q
    const int h  = bh & 7;
    const int t  = threadIdx.x;
    const int w  = t >> 6, lane = t & 63;
    const int g  = lane >> 4, qi = lane & 15;
    const int xq = (qi & 7) << 3;
    const int qbase = qt * 128 + w * 32;

    __shared__ __align__(16) __bf16 lds[16384];
    __bf16* Vl = lds;                    // 4096
    __bf16* Pw = lds + 4096 + w * 2048;  // per-wave 2048
    __bf16* R0 = lds + 12288;            // 2048
    __bf16* R1 = lds + 14336;            // 2048

    // copy this head's precomputed reversed tables (R0|R1 contiguous, 4096 bf16)
    {
        const __bf16* src = rtab + (size_t)h * 4096;
        #pragma unroll
        for (int i = 0; i < 2; i++) {
            int e = (i * 256 + t) * 8;
            *(bf16x8*)&lds[12288 + e] = *(const bf16x8*)&src[e];
        }
    }

    bf16x8 qf[2];
    {
        union { unsigned u[4]; bf16x8 v8; } uz;
        uz.u[0] = uz.u[1] = uz.u[2] = uz.u[3] = 0u;
        #pragma unroll
        for (int n = 0; n < 2; n++) {
            qf[n] = uz.v8;
            if (g < 2)
                qf[n] = *(const bf16x8*)&q[((size_t)bh * LL + qbase + n * 16 + qi) * DHH + g * 8];
        }
    }

    f32x4 accp[2], accb[2];
    #pragma unroll
    for (int n = 0; n < 2; n++) {
        accp[n] = (f32x4){0.f, 0.f, 0.f, 0.f};
        accb[n] = (f32x4){0.f, 0.f, 0.f, 0.f};
    }
    float mrun[2] = {-INFINITY, -INFINITY};
    float lrun[2] = {0.f, 0.f};

    const f32x4 zero4 = (f32x4){0.f, 0.f, 0.f, 0.f};

// S is in log2 domain (q pre-scaled by 1/sqrt(128)*log2e) -> bare v_exp_f32
#define PROC_N(Sn, n) do { \
    float mx = Sn[0][0]; \
    _Pragma("unroll") \
    for (int f = 0; f < 8; f++) { \
        _Pragma("unroll") \
        for (int r = 0; r < 4; r++) if (f || r) mx = fmaxf(mx, Sn[f][r]); } \
    mx = fmaxf(mx, __shfl_xor(mx, 16, 64)); \
    mx = fmaxf(mx, __shfl_xor(mx, 32, 64)); \
    float mnew = fmaxf(mrun[n], mx); \
    float sf = __builtin_amdgcn_exp2f(mrun[n] - mnew); \
    mrun[n] = mnew; \
    lrun[n] *= sf; \
    accp[n][0] *= sf; accp[n][1] *= sf; accp[n][2] *= sf; accp[n][3] *= sf; \
    float ls = 0.f; \
    _Pragma("unroll") \
    for (int f = 0; f < 8; f++) { \
        float p0 = __builtin_amdgcn_exp2f(Sn[f][0] - mnew); \
        float p1 = __builtin_amdgcn_exp2f(Sn[f][1] - mnew); \
        float p2 = __builtin_amdgcn_exp2f(Sn[f][2] - mnew); \
        float p3 = __builtin_amdgcn_exp2f(Sn[f][3] - mnew); \
        ls += (p0 + p1) + (p2 + p3); \
        unsigned* pp = (unsigned*)(Pw + (qi * 128 + ((f * 16 + g * 4) ^ xq))); \
        pp[0] = pkbf(p0, p1); pp[1] = pkbf(p2, p3); \
    } \
    ls += __shfl_xor(ls, 16, 64); ls += __shfl_xor(ls, 32, 64); \
    lrun[n] += ls; \
    int qoff = 1023 - (qbase + (n) * 16 + qi) + k0; \
    _Pragma("unroll") \
    for (int c = 0; c < 4; c++) { \
        bf16x8 vf = *(const bf16x8*)&Vbuf[qi * 128 + ((c * 32 + g * 8) ^ xq)]; \
        bf16x8 pf = *(const bf16x8*)&Pw[qi * 128 + ((c * 32 + g * 8) ^ xq)]; \
        int idx = qoff + c * 32 + 8 * g; \
        const unsigned* tb = (const unsigned*)((idx & 1) ? R1 : R0); \
        unsigned s_ = (unsigned)idx >> 1; \
        union { unsigned u[4]; bf16x8 v8; } bu; \
        bu.u[0] = tb[s_]; bu.u[1] = tb[s_ + 1]; \
        bu.u[2] = tb[s_ + 2]; bu.u[3] = tb[s_ + 3]; \
        accp[n] = __builtin_amdgcn_mfma_f32_16x16x32_bf16(vf, pf, accp[n], 0, 0, 0); \
        accb[n] = __builtin_amdgcn_mfma_f32_16x16x32_bf16(vf, bu.v8, accb[n], 0, 0, 0); \
    } \
} while (0)

    for (int kt = 0; kt < 8; kt++) {
        const int k0 = kt * 128;
        {
            int kr = t >> 1, d0 = (t & 1) * 8;
            bf16x8 b8 = *(const bf16x8*)&v[((size_t)bh * LL + k0 + kr) * DHH + d0];
            __bf16* dst = Vl + (kt & 1) * 2048;
            #pragma unroll
            for (int i = 0; i < 8; i++) {
                int d = d0 + i;
                dst[d * 128 + (kr ^ ((d & 7) << 3))] = b8[i];
            }
        }
        __syncthreads();
        const __bf16* Vbuf = Vl + (kt & 1) * 2048;

        f32x4 S0[8], S1[8];
        #pragma unroll
        for (int f = 0; f < 8; f++) {
            bf16x8 kf = *(const bf16x8*)&k[((size_t)bh * LL + k0 + f * 16 + qi) * DHH + (g & 1) * 8];
            S0[f] = __builtin_amdgcn_mfma_f32_16x16x32_bf16(kf, qf[0], zero4, 0, 0, 0);
            S1[f] = __builtin_amdgcn_mfma_f32_16x16x32_bf16(kf, qf[1], zero4, 0, 0, 0);
        }

        PROC_N(S0, 0);
        PROC_N(S1, 1);
    }
#undef PROC_N

    #pragma unroll
    for (int n = 0; n < 2; n++) {
        float inv = 1.0f / lrun[n];
        float4 o;
        o.x = accp[n][0] * inv + accb[n][0];
        o.y = accp[n][1] * inv + accb[n][1];
        o.z = accp[n][2] * inv + accb[n][2];
        o.w = accp[n][3] * inv + accb[n][3];
        *(float4*)&out[((size_t)bh * LL + qbase + n * 16 + qi) * DHH + g * 4] = o;
    }
}

// ---------- fused: LN(attn_out); att = LN(xsrc + .); ff1 = relu(att @ w1^T + b1) ----------
// 512 threads; phase 1 = double-LN into attb + bf16 Ax tile; phase 2 = MFMA GEMM
__global__ __launch_bounds__(512) void k_lnff1(
    const float* __restrict__ ao,  const float* __restrict__ xsrc,
    const float* __restrict__ lag, const float* __restrict__ lab,
    const float* __restrict__ l1g, const float* __restrict__ l1b,
    const __bf16* __restrict__ w1fbf, const float* __restrict__ b1f,
    float* __restrict__ attb, __bf16* __restrict__ ff1b)
{
    const int lt = blockIdx.x, b = blockIdx.y;
    const int t = threadIdx.x;
    const int l0 = lt * 64;

    __shared__ float tile[64][132];
    __shared__ __align__(16) __bf16 Ax[64 * 128];

    // gather attn-out heads into tile[l][d]
    #pragma unroll
    for (int u = 0; u < 2; u++) {
        int cid = u * 512 + t;               // 1024 chunks of 8
        int hh = cid >> 7, rem = cid & 127;
        int l = rem >> 1, dh0 = (rem & 1) * 8;
        const float* src = &ao[(((size_t)b * NHH + hh) * LL + l0 + l) * DHH + dh0];
        float4 a0 = *(const float4*)src;
        float4 a1 = *(const float4*)(src + 4);
        *(float4*)&tile[l][hh * 16 + dh0]     = a0;
        *(float4*)&tile[l][hh * 16 + dh0 + 4] = a1;
    }
    __syncthreads();

    const int wid = t >> 6, lane = t & 63;
    {
        float2 ga  = *(const float2*)&lag[lane * 2];
        float2 ba  = *(const float2*)&lab[lane * 2];
        float2 g1v = *(const float2*)&l1g[lane * 2];
        float2 b1v = *(const float2*)&l1b[lane * 2];

        for (int rr = 0; rr < 8; rr++) {
            int r = wid * 8 + rr;
            float2 vv = *(const float2*)&tile[r][lane * 2];
            float s = vv.x + vv.y, s2 = vv.x * vv.x + vv.y * vv.y;
            #pragma unroll
            for (int m = 1; m < 64; m <<= 1) { s += __shfl_xor(s, m, 64); s2 += __shfl_xor(s2, m, 64); }
            float mu = s * (1.f / 128.f);
            float var = s2 * (1.f / 128.f) - mu * mu;
            float rs = rsqrtf(var + 1e-5f);
            float o0 = (vv.x - mu) * rs * ga.x + ba.x;
            float o1 = (vv.y - mu) * rs * ga.y + ba.y;
            float2 xv = *(const float2*)&xsrc[((size_t)b * LL + l0 + r) * DD + lane * 2];
            float t0 = xv.x + o0, t1 = xv.y + o1;
            s = t0 + t1; s2 = t0 * t0 + t1 * t1;
            #pragma unroll
            for (int m = 1; m < 64; m <<= 1) { s += __shfl_xor(s, m, 64); s2 += __shfl_xor(s2, m, 64); }
            mu = s * (1.f / 128.f);
            var = s2 * (1.f / 128.f) - mu * mu;
            rs = rsqrtf(var + 1e-5f);
            float a0 = (t0 - mu) * rs * g1v.x + b1v.x;
            float a1 = (t1 - mu) * rs * g1v.y + b1v.y;
            float2 o = {a0, a1};
            *(float2*)&attb[((size_t)b * LL + l0 + r) * DD + lane * 2] = o;
            *(unsigned*)&Ax[r * 128 + ((lane * 2) ^ (SWZ(r) << 3))] = pkbf(a0, a1);
        }
    }
    __syncthreads();

    // ---- GEMM phase (identical to previous k_ff1) ----
    const int w = wid;
    const int l15 = lane & 15, kg = lane >> 4;

    bf16x8 breg[16];
    #pragma unroll
    for (int nf = 0; nf < 4; nf++)
        #pragma unroll
        for (int kk = 0; kk < 4; kk++)
            breg[nf * 4 + kk] = *(const bf16x8*)&w1fbf[
                (size_t)(w * 64 + nf * 16 + l15) * 128 + kk * 32 + kg * 8];

    f32x4 acc[4][4];
    #pragma unroll
    for (int mf = 0; mf < 4; mf++)
        #pragma unroll
        for (int nf = 0; nf < 4; nf++) acc[mf][nf] = (f32x4){0.f, 0.f, 0.f, 0.f};

    #pragma unroll
    for (int kk = 0; kk < 4; kk++) {
        int kb = kk * 32 + kg * 8;
        bf16x8 af[4];
        #pragma unroll
        for (int mf = 0; mf < 4; mf++) {
            int r = mf * 16 + l15;
            af[mf] = *(const bf16x8*)&Ax[r * 128 + (kb ^ (SWZ(r) << 3))];
        }
        #pragma unroll
        for (int mf = 0; mf < 4; mf++)
            #pragma unroll
            for (int nf = 0; nf < 4; nf++)
                acc[mf][nf] = __builtin_amdgcn_mfma_f32_16x16x32_bf16(
                    af[mf], breg[nf * 4 + kk], acc[mf][nf], 0, 0, 0);
    }

    #pragma unroll
    for (int nf = 0; nf < 4; nf++) {
        int n = w * 64 + nf * 16 + l15;
        float bias = b1f[n];
        #pragma unroll
        for (int mf = 0; mf < 4; mf++) {
            #pragma unroll
            for (int r = 0; r < 4; r++) {
                int l = l0 + mf * 16 + kg * 4 + r;
                float vv = fmaxf(acc[mf][nf][r] + bias, 0.0f);
                ff1b[((size_t)b * LL + l) * DF + n] = (__bf16)vv;
            }
        }
    }
}

// ---------- ff2 (MFMA, K=512) + bias + residual + LN2 + transpose-store ----------
__global__ __launch_bounds__(512) void k_ff2(
    const __bf16* __restrict__ ff1b, const __bf16* __restrict__ w2fbf,
    const float* __restrict__ b2f, const float* __restrict__ att,
    const float* __restrict__ l2g, const float* __restrict__ l2b,
    float* __restrict__ y)
{
    const int lt = blockIdx.x, b = blockIdx.y;
    const int t = threadIdx.x;
    const int l0 = lt * 64;

    __shared__ __align__(16) __bf16 Ax[64 * 512];   // 64KB; reused as yl after GEMM
    float* yl = (float*)Ax;                          // [64][132] overlay

    #pragma unroll
    for (int it = 0; it < 8; it++) {
        int g8 = it * 512 + t;                       // 4096 granules of 8
        int l = g8 >> 6, c8 = g8 & 63;
        bf16x8 v8 = *(const bf16x8*)&ff1b[((size_t)b * LL + l0 + l) * DF + c8 * 8];
        *(bf16x8*)&Ax[l * 512 + ((c8 * 8) ^ (SWZ(l) << 3))] = v8;
    }
    __syncthreads();

    const int w = t >> 6, lane = t & 63;
    const int l15 = lane & 15, kg = lane >> 4;
    const int d = w * 16 + l15;

    bf16x8 breg[16];
    #pragma unroll
    for (int kk = 0; kk < 16; kk++)
        breg[kk] = *(const bf16x8*)&w2fbf[(size_t)d * DF + kk * 32 + kg * 8];

    f32x4 acc[4];
    #pragma unroll
    for (int mf = 0; mf < 4; mf++) acc[mf] = (f32x4){0.f, 0.f, 0.f, 0.f};

    #pragma unroll
    for (int kk = 0; kk < 16; kk++) {
        int kb = kk * 32 + kg * 8;
        #pragma unroll
        for (int mf = 0; mf < 4; mf++) {
            int r = mf * 16 + l15;
            bf16x8 af = *(const bf16x8*)&Ax[r * 512 + (kb ^ (SWZ(r) << 3))];
            acc[mf] = __builtin_amdgcn_mfma_f32_16x16x32_bf16(af, breg[kk], acc[mf], 0, 0, 0);
        }
    }
    __syncthreads();   // Ax reads done; overlay as yl

    {
        float bias = b2f[d];
        #pragma unroll
        for (int mf = 0; mf < 4; mf++) {
            #pragma unroll
            for (int r = 0; r < 4; r++) {
                int l = mf * 16 + kg * 4 + r;
                float res = att[((size_t)b * LL + l0 + l) * DD + d];
                yl[l * 132 + d] = acc[mf][r] + bias + res;
            }
        }
    }
    __syncthreads();

    const int wid = t >> 6;
    float2 gv = *(const float2*)&l2g[lane * 2];
    float2 bv = *(const float2*)&l2b[lane * 2];
    for (int rr = 0; rr < 8; rr++) {
        int r = wid * 8 + rr;
        float2 vv = *(const float2*)&yl[r * 132 + lane * 2];
        float s = vv.x + vv.y, s2 = vv.x * vv.x + vv.y * vv.y;
        #pragma unroll
        for (int m = 1; m < 64; m <<= 1) { s += __shfl_xor(s, m, 64); s2 += __shfl_xor(s2, m, 64); }
        float mu = s * (1.f / 128.f);
        float var = s2 * (1.f / 128.f) - mu * mu;
        float rs = rsqrtf(var + 1e-5f);
        float o0 = (vv.x - mu) * rs * gv.x + bv.x;
        float o1 = (vv.y - mu) * rs * gv.y + bv.y;
        yl[r * 132 + lane * 2]     = o0;
        yl[r * 132 + lane * 2 + 1] = o1;
    }
    __syncthreads();

    {
        int dd = t >> 2, lh = (t & 3) * 16;
        #pragma unroll
        for (int i0 = 0; i0 < 16; i0 += 4) {
            float4 o = { yl[(lh + i0 + 0) * 132 + dd], yl[(lh + i0 + 1) * 132 + dd],
                         yl[(lh + i0 + 2) * 132 + dd], yl[(lh + i0 + 3) * 132 + dd] };
            *(float4*)&y[(size_t)b * DD * LL + (size_t)dd * LL + l0 + lh + i0] = o;
        }
    }
}

extern "C" void kernel_launch(void* const* d_in, const int* in_sizes, int n_in,
                              void* d_out, int out_size, void* d_ws, size_t ws_size,
                              hipStream_t stream)
{
    const float* x   = (const float*)d_in[0];
    const float* c1w = (const float*)d_in[1];
    const float* c1b = (const float*)d_in[2];
    const float* g1  = (const float*)d_in[3];
    const float* bb1 = (const float*)d_in[4];
    const float* c2w = (const float*)d_in[5];
    const float* c2b = (const float*)d_in[6];
    const float* g2  = (const float*)d_in[7];
    const float* bb2 = (const float*)d_in[8];
    const float* wq  = (const float*)d_in[9];
    const float* wk  = (const float*)d_in[10];
    const float* wv  = (const float*)d_in[11];
    const float* rel = (const float*)d_in[12];
    const float* lag = (const float*)d_in[13];
    const float* lab = (const float*)d_in[14];
    const float* l1g = (const float*)d_in[15];
    const float* l1b = (const float*)d_in[16];
    const float* l2g = (const float*)d_in[17];
    const float* l2b = (const float*)d_in[18];
    const float* w1f = (const float*)d_in[19];
    const float* b1f = (const float*)d_in[20];
    const float* w2f = (const float*)d_in[21];
    const float* b2f = (const float*)d_in[22];

    char* W = (char*)d_ws;
    const size_t MB = 1ull << 20;
    float*  xsrc   = (float*)(W);
    float*  abuf   = (float*)(W + 8 * MB);
    float*  attb   = (float*)(W + 16 * MB);
    __bf16* qbuf   = (__bf16*)(W + 24 * MB);
    __bf16* kbuf   = (__bf16*)(W + 28 * MB);
    __bf16* vbuf   = (__bf16*)(W + 32 * MB);
    __bf16* ff1b   = (__bf16*)(W + 36 * MB);
    __bf16* w2bf   = (__bf16*)(W + 52 * MB);
    __bf16* wallbf = (__bf16*)(W + 54 * MB);
    __bf16* w1fbf  = (__bf16*)(W + 54 * MB + 128 * 1024);
    __bf16* w2fbf  = (__bf16*)(W + 54 * MB + 256 * 1024);
    float*  peb    = (float*)(W + 54 * MB + 384 * 1024);
    float*  w1A    = (float*)(W + 54 * MB + 896 * 1024);
    float*  b1A    = (float*)(W + 54 * MB + 912 * 1024);
    __bf16* rtab   = (__bf16*)(W + 54 * MB + 928 * 1024);   // 8 heads x 4096 bf16 = 64KB

    k_prep<<<dim3(1489), dim3(256), 0, stream>>>(
        c2w, wq, wk, wv, w1f, w2f, c1w, c1b, g1, bb1, rel,
        w2bf, wallbf, w1fbf, w2fbf, peb, w1A, b1A, rtab);
    k_conv<<<dim3(32, 16), dim3(512), 0, stream>>>(x, w1A, b1A, w2bf, c2b, g2, bb2, xsrc);
    k_qkv<<<dim3(16, 16), dim3(384), 0, stream>>>(xsrc, peb, wallbf, qbuf, kbuf, vbuf);
    k_attn<<<dim3(128, 8), dim3(256), 0, stream>>>(qbuf, kbuf, vbuf, rtab, abuf);
    k_lnff1<<<dim3(16, 16), dim3(512), 0, stream>>>(
        abuf, xsrc, lag, lab, l1g, l1b, w1fbf, b1f, attb, ff1b);
    k_ff2<<<dim3(16, 16), dim3(512), 0, stream>>>(ff1b, w2fbf, b2f, attb, l2g, l2b, (float*)d_out);
}